// Round 2
// baseline (3763.155 us; speedup 1.0000x reference)
//
#include <hip/hip_runtime.h>
#include <math.h>

#define NN 2304
#define BB 16
#define CC 256
#define DI 512
#define MM (BB*NN)   // 36864

typedef __attribute__((ext_vector_type(8))) short bf16x8;
typedef __attribute__((ext_vector_type(4))) float f32x4;

__device__ inline unsigned short f2b(float f){
  unsigned u = __float_as_uint(f);
  u = u + 0x7FFFu + ((u>>16)&1u);
  return (unsigned short)(u>>16);
}
__device__ inline float b2f(unsigned short s){ return __uint_as_float(((unsigned)s)<<16); }

// ---------------- weight convert / transpose ----------------
__global__ __launch_bounds__(256) void k_wconv(const float* __restrict__ in, unsigned short* __restrict__ out, int R, int Ccols){
  int idx = blockIdx.x*256 + threadIdx.x;
  if (idx >= R*Ccols) return;
  int r = idx / Ccols, c = idx - r*Ccols;
  out[(size_t)c*R + r] = f2b(in[idx]);
}
__global__ __launch_bounds__(256) void k_t32(const float* __restrict__ in, float* __restrict__ out, int R, int Ccols){
  int idx = blockIdx.x*256 + threadIdx.x;
  if (idx >= R*Ccols) return;
  int r = idx / Ccols, c = idx - r*Ccols;
  out[(size_t)c*R + r] = in[idx];
}

// ---------------- feature norms ----------------
__global__ __launch_bounds__(256) void k_norm(const float* __restrict__ x, float* __restrict__ innorm){
  int row = blockIdx.x*4 + (threadIdx.x>>6); int lane = threadIdx.x&63;
  float4 v = *(const float4*)(x + (size_t)row*CC + lane*4);
  float s = v.x*v.x + v.y*v.y + v.z*v.z + v.w*v.w;
  #pragma unroll
  for (int o=32;o;o>>=1) s += __shfl_xor(s,o);
  if (lane==0) innorm[row] = 1.0f/(sqrtf(s)+1e-8f);
}

// ---------------- edge weights exp(1-cos) ----------------
__global__ __launch_bounds__(256) void k_edge(const float* __restrict__ x, const float* __restrict__ innorm, float* __restrict__ wgt){
  int g = blockIdx.x*4 + (threadIdx.x>>6); int lane = threadIdx.x&63;
  int b = g/NN, n = g - b*NN;
  int r = n/48, c = n - (n/48)*48;
  const float* xb = x + ((size_t)b*NN)*CC;
  float4 vu = *(const float4*)(xb + (size_t)n*CC + lane*4);
  int nb0=(r>0)?n-48:-1, nb1=(r<47)?n+48:-1, nb2=(c>0)?n-1:-1, nb3=(c<47)?n+1:-1;
  float d0=0,d1=0,d2=0,d3=0;
  if (nb0>=0){ float4 t=*(const float4*)(xb+(size_t)nb0*CC+lane*4); d0=vu.x*t.x+vu.y*t.y+vu.z*t.z+vu.w*t.w; }
  if (nb1>=0){ float4 t=*(const float4*)(xb+(size_t)nb1*CC+lane*4); d1=vu.x*t.x+vu.y*t.y+vu.z*t.z+vu.w*t.w; }
  if (nb2>=0){ float4 t=*(const float4*)(xb+(size_t)nb2*CC+lane*4); d2=vu.x*t.x+vu.y*t.y+vu.z*t.z+vu.w*t.w; }
  if (nb3>=0){ float4 t=*(const float4*)(xb+(size_t)nb3*CC+lane*4); d3=vu.x*t.x+vu.y*t.y+vu.z*t.z+vu.w*t.w; }
  #pragma unroll
  for (int o=32;o;o>>=1){ d0+=__shfl_xor(d0,o); d1+=__shfl_xor(d1,o); d2+=__shfl_xor(d2,o); d3+=__shfl_xor(d3,o); }
  if (lane==0){
    float inu = innorm[g];
    float inf_ = __uint_as_float(0x7F800000u);
    float4 w;
    w.x = (nb0>=0)? expf(1.0f - d0*(inu*innorm[g-n+nb0])) : inf_;
    w.y = (nb1>=0)? expf(1.0f - d1*(inu*innorm[g-n+nb1])) : inf_;
    w.z = (nb2>=0)? expf(1.0f - d2*(inu*innorm[g-n+nb2])) : inf_;
    w.w = (nb3>=0)? expf(1.0f - d3*(inu*innorm[g-n+nb3])) : inf_;
    *(float4*)(wgt + (size_t)g*4) = w;
  }
}

// ---------------- Prim MST, exact reference tie-breaking ----------------
__global__ __launch_bounds__(64) void k_prim(const float* __restrict__ wgt, int* __restrict__ par_g,
      int* __restrict__ lvlorder, int* __restrict__ lvlstart, int* __restrict__ nlvl)
{
  __shared__ unsigned long long key[NN];
  __shared__ int par[NN];
  __shared__ unsigned short dep[NN];
  __shared__ int hist[NN+1];
  int b = blockIdx.x, lane = threadIdx.x;
  const float* wb = wgt + (size_t)b*NN*4;
  unsigned long long smin = ~0ULL;
  for (int j=0;j<36;j++){
    int i = lane*36+j;
    unsigned long long kv = (i==0) ? 0ULL : ((0x7F800000ULL<<32) | (unsigned)i);
    key[i]=kv; par[i]=0;
    if (kv<smin) smin=kv;
  }
  __syncthreads();
  int maxd=0;
  for (int step=0; step<NN; step++){
    unsigned long long m = smin;
    #pragma unroll
    for (int o=32;o;o>>=1){
      unsigned lo = (unsigned)__shfl_xor((int)(unsigned)m, o);
      unsigned hi = (unsigned)__shfl_xor((int)(unsigned)(m>>32), o);
      unsigned long long t = ((unsigned long long)hi<<32)|lo;
      if (t<m) m=t;
    }
    int u = (int)(unsigned)m;
    if (lane==0){
      int du = (step==0)?0:((int)dep[par[u]]+1);
      dep[u]=(unsigned short)du;
      if (du>maxd) maxd=du;
    }
    int owner = u/36;
    if (lane==owner) key[u]=~0ULL;
    __syncthreads();
    unsigned long long t = (lane<36)? key[owner*36+lane] : ~0ULL;
    #pragma unroll
    for (int o=32;o;o>>=1){
      unsigned lo = (unsigned)__shfl_xor((int)(unsigned)t, o);
      unsigned hi = (unsigned)__shfl_xor((int)(unsigned)(t>>32), o);
      unsigned long long q=((unsigned long long)hi<<32)|lo;
      if (q<t) t=q;
    }
    if (lane==owner) smin=t;
    int r = u/48, c = u - (u/48)*48;
    float4 w4 = *(const float4*)(wb + (size_t)u*4);
    int nb0=(r>0)?u-48:-1, nb1=(r<47)?u+48:-1, nb2=(c>0)?u-1:-1, nb3=(c<47)?u+1:-1;
    unsigned long long k0 = (nb0>=0)? key[nb0] : 0ULL;
    unsigned long long k1 = (nb1>=0)? key[nb1] : 0ULL;
    unsigned long long k2 = (nb2>=0)? key[nb2] : 0ULL;
    unsigned long long k3 = (nb3>=0)? key[nb3] : 0ULL;
    unsigned long long p0 = ((unsigned long long)__float_as_uint(w4.x)<<32)|(unsigned)nb0;
    unsigned long long p1 = ((unsigned long long)__float_as_uint(w4.y)<<32)|(unsigned)nb1;
    unsigned long long p2 = ((unsigned long long)__float_as_uint(w4.z)<<32)|(unsigned)nb2;
    unsigned long long p3 = ((unsigned long long)__float_as_uint(w4.w)<<32)|(unsigned)nb3;
    bool u0 = (nb0>=0) && (k0!=~0ULL) && (p0<k0);
    bool u1 = (nb1>=0) && (k1!=~0ULL) && (p1<k1);
    bool u2 = (nb2>=0) && (k2!=~0ULL) && (p2<k2);
    bool u3 = (nb3>=0) && (k3!=~0ULL) && (p3<k3);
    if (lane==0){
      if (u0){ key[nb0]=p0; par[nb0]=u; }
      if (u1){ key[nb1]=p1; par[nb1]=u; }
      if (u2){ key[nb2]=p2; par[nb2]=u; }
      if (u3){ key[nb3]=p3; par[nb3]=u; }
    }
    if (u0 && lane==nb0/36 && p0<smin) smin=p0;
    if (u1 && lane==nb1/36 && p1<smin) smin=p1;
    if (u2 && lane==nb2/36 && p2<smin) smin=p2;
    if (u3 && lane==nb3/36 && p3<smin) smin=p3;
    __syncthreads();
  }
  maxd = __shfl(maxd,0);
  int nlv = maxd+1;
  for (int i=lane;i<=nlv;i+=64) hist[i]=0;
  __syncthreads();
  for (int j=0;j<36;j++) atomicAdd(&hist[dep[lane*36+j]],1);
  __syncthreads();
  if (lane==0){
    int run=0;
    for (int l=0;l<nlv;l++){ int cnt=hist[l]; hist[l]=run; lvlstart[b*(NN+2)+l]=run; run+=cnt; }
    lvlstart[b*(NN+2)+nlv]=run;
    nlvl[b]=nlv;
  }
  __syncthreads();
  for (int j=0;j<36;j++){
    int i=lane*36+j;
    int pos=atomicAdd(&hist[dep[i]],1);
    lvlorder[b*NN+pos]=i;
  }
  for (int i=lane;i<NN;i+=64) par_g[b*NN+i]=par[i];
}

// ---------------- LayerNorm -> bf16 ----------------
__global__ __launch_bounds__(256) void k_ln(const float* __restrict__ xin, const float* __restrict__ g,
    const float* __restrict__ bta, unsigned short* __restrict__ outb)
{
  int row = blockIdx.x*4 + (threadIdx.x>>6); int lane=threadIdx.x&63;
  float4 v = *(const float4*)(xin + (size_t)row*CC + lane*4);
  float s = v.x+v.y+v.z+v.w;
  #pragma unroll
  for (int o=32;o;o>>=1) s += __shfl_xor(s,o);
  float m = s*(1.0f/256.0f);
  float dx=v.x-m, dy=v.y-m, dz=v.z-m, dw=v.w-m;
  float ss=dx*dx+dy*dy+dz*dz+dw*dw;
  #pragma unroll
  for (int o=32;o;o>>=1) ss += __shfl_xor(ss,o);
  float rs = rsqrtf(ss*(1.0f/256.0f)+1e-5f);
  int cb=lane*4;
  unsigned o0 = (unsigned)f2b(dx*rs*g[cb+0]+bta[cb+0]) | ((unsigned)f2b(dy*rs*g[cb+1]+bta[cb+1])<<16);
  unsigned o1 = (unsigned)f2b(dz*rs*g[cb+2]+bta[cb+2]) | ((unsigned)f2b(dw*rs*g[cb+3]+bta[cb+3])<<16);
  *(uint2*)(outb + (size_t)row*CC + cb) = make_uint2(o0,o1);
}

// ---------------- bf16 MFMA GEMM, 128x128 tile, fused epilogues ----------------
// EPI 0: silu-split to bout0 (col<512) / bout1 (col>=512), both bf16 [M][512]
// EPI 1: fout = addin + (acc+bias), f32 [M][Ndim]
// EPI 2: bout0 = bf16(gelu(acc+bias)), [M][Ndim]
template<int EPI>
__global__ __launch_bounds__(256) void k_gemm(
    const unsigned short* __restrict__ A, const unsigned short* __restrict__ BT,
    const float* __restrict__ bias, int Ndim, int K,
    const float* __restrict__ addin, float* __restrict__ fout,
    unsigned short* __restrict__ bout0, unsigned short* __restrict__ bout1)
{
  __shared__ __align__(16) unsigned short lA[128*32];
  __shared__ __align__(16) unsigned short lB[128*32];
  int tid=threadIdx.x, wid=tid>>6, lane=tid&63;
  int ntn = Ndim>>7;
  int bm = blockIdx.x/ntn, bn = blockIdx.x - bm*ntn;
  const unsigned short* Ab = A + (size_t)bm*128*K;
  const unsigned short* Bb = BT + (size_t)bn*128*K;
  int wr=wid>>1, wc=wid&1;
  f32x4 acc[4][4];
  #pragma unroll
  for (int m2=0;m2<4;m2++)
    #pragma unroll
    for (int n2=0;n2<4;n2++)
      #pragma unroll
      for (int j=0;j<4;j++) acc[m2][n2][j]=0.f;
  int r0 = tid>>2, c0 = (tid&3)*8;
  for (int k0=0;k0<K;k0+=32){
    int4 va0 = *(const int4*)(Ab + (size_t)r0*K + k0 + c0);
    int4 va1 = *(const int4*)(Ab + (size_t)(r0+64)*K + k0 + c0);
    int4 vb0 = *(const int4*)(Bb + (size_t)r0*K + k0 + c0);
    int4 vb1 = *(const int4*)(Bb + (size_t)(r0+64)*K + k0 + c0);
    __syncthreads();
    *(int4*)(lA + r0*32 + c0) = va0;
    *(int4*)(lA + (r0+64)*32 + c0) = va1;
    *(int4*)(lB + r0*32 + c0) = vb0;
    *(int4*)(lB + (r0+64)*32 + c0) = vb1;
    __syncthreads();
    int ra = (wr<<6) + (lane&15);
    int rb = (wc<<6) + (lane&15);
    int cb = (lane>>4)<<3;
    bf16x8 af[4], bfr[4];
    #pragma unroll
    for (int m2=0;m2<4;m2++) af[m2] = *(const bf16x8*)(lA + (ra+m2*16)*32 + cb);
    #pragma unroll
    for (int n2=0;n2<4;n2++) bfr[n2] = *(const bf16x8*)(lB + (rb+n2*16)*32 + cb);
    #pragma unroll
    for (int m2=0;m2<4;m2++)
      #pragma unroll
      for (int n2=0;n2<4;n2++)
        acc[m2][n2] = __builtin_amdgcn_mfma_f32_16x16x32_bf16(af[m2], bfr[n2], acc[m2][n2], 0,0,0);
  }
  int rr = (lane>>4)<<2, cc = lane&15;
  #pragma unroll
  for (int m2=0;m2<4;m2++){
    #pragma unroll
    for (int n2=0;n2<4;n2++){
      int col = (bn<<7) + (wc<<6) + (n2<<4) + cc;
      float bs = bias[col];
      #pragma unroll
      for (int j=0;j<4;j++){
        int row = (bm<<7) + (wr<<6) + (m2<<4) + rr + j;
        float v = acc[m2][n2][j] + bs;
        if (EPI==0){
          float sv = v * (1.0f/(1.0f+expf(-v)));
          if (col < DI) bout0[(size_t)row*DI + col] = f2b(sv);
          else          bout1[(size_t)row*DI + col - DI] = f2b(sv);
        } else if (EPI==1){
          size_t oi=(size_t)row*Ndim+col;
          fout[oi] = addin[oi] + v;
        } else {
          size_t oi=(size_t)row*Ndim+col;
          bout0[oi] = f2b(0.5f*v*(1.0f+erff(v*0.70710678118f)));
        }
      }
    }
  }
}

// ---------------- dbc = xi @ W_xp  (18 cols) ----------------
__global__ __launch_bounds__(256) void k_dbc(const unsigned short* __restrict__ xi_b,
    const float* __restrict__ WxpT, float* __restrict__ dbc)
{
  int row = blockIdx.x*4 + (threadIdx.x>>6); int lane=threadIdx.x&63;
  int4 raw = *(const int4*)(xi_b + (size_t)row*DI + lane*8);
  float xf[8];
  xf[0]=b2f((unsigned short)((unsigned)raw.x&0xFFFFu)); xf[1]=b2f((unsigned short)((unsigned)raw.x>>16));
  xf[2]=b2f((unsigned short)((unsigned)raw.y&0xFFFFu)); xf[3]=b2f((unsigned short)((unsigned)raw.y>>16));
  xf[4]=b2f((unsigned short)((unsigned)raw.z&0xFFFFu)); xf[5]=b2f((unsigned short)((unsigned)raw.z>>16));
  xf[6]=b2f((unsigned short)((unsigned)raw.w&0xFFFFu)); xf[7]=b2f((unsigned short)((unsigned)raw.w>>16));
  for (int jc=0;jc<18;jc++){
    const float* wr_ = WxpT + (size_t)jc*DI + lane*8;
    float s=0.f;
    #pragma unroll
    for (int t=0;t<8;t++) s += xf[t]*wr_[t];
    #pragma unroll
    for (int o=32;o;o>>=1) s += __shfl_xor(s,o);
    if (lane==0) dbc[(size_t)row*18+jc]=s;
  }
}

// ---------------- dt/softplus -> decay (bf16), Bx (bf16) ----------------
__global__ __launch_bounds__(512) void k_dbx(const float* __restrict__ dbc, const unsigned short* __restrict__ xi_b,
  const float* __restrict__ W_dt, const float* __restrict__ b_dt, const float* __restrict__ A_log,
  unsigned short* __restrict__ decay, unsigned short* __restrict__ Bx)
{
  int row=blockIdx.x, c=threadIdx.x;
  __shared__ float sd[18];
  if (c<18) sd[c]=dbc[(size_t)row*18+c];
  __syncthreads();
  float a=b_dt[c];
  #pragma unroll
  for (int r2=0;r2<16;r2++) a += sd[r2]*W_dt[r2*DI+c];
  float dt = (a>20.f)? a : log1pf(expf(a));
  size_t o=(size_t)row*DI+c;
  decay[o]=f2b(expf(dt * -expf(A_log[c])));
  Bx[o]=f2b(dt*sd[16]*b2f(xi_b[o]));
}

// ---------------- level-parallel tree scan, in place over Bx ----------------
__global__ __launch_bounds__(1024) void k_scan(const unsigned short* __restrict__ decay,
    unsigned short* __restrict__ bxh,
    const int* __restrict__ par_g, const int* __restrict__ lvlorder, const int* __restrict__ lvlstart,
    const int* __restrict__ nlvl)
{
  int b=blockIdx.x, tid=threadIdx.x;
  const size_t base=(size_t)b*NN*DI;
  int nlv = nlvl[b];
  // level 0 = root (node 0): h = Bx, already in place
  for (int lvl=1; lvl<nlv; lvl++){
    int s=lvlstart[b*(NN+2)+lvl], e=lvlstart[b*(NN+2)+lvl+1];
    int tot=(e-s)<<9;
    for (int idx=tid; idx<tot; idx+=1024){
      int node = lvlorder[b*NN + s + (idx>>9)];
      int cch = idx&511;
      int pv = par_g[b*NN+node];
      size_t o = base + ((size_t)node<<9) + cch;
      float hv = b2f(decay[o])*b2f(bxh[base + ((size_t)pv<<9) + cch]) + b2f(bxh[o]);
      bxh[o] = f2b(hv);
    }
    __syncthreads();
  }
}

// ---------------- u = (Cv*h + Dp*xi) * silu(z) -> bf16 (in place over sz) ----------------
__global__ __launch_bounds__(256) void k_u(const unsigned short* __restrict__ h, const unsigned short* __restrict__ xi_b,
    const unsigned short* __restrict__ sz_b, const float* __restrict__ dbc, const float* __restrict__ Dp,
    unsigned short* __restrict__ u_b)
{
  int g8 = blockIdx.x*256 + threadIdx.x;
  int row = g8>>6; int cb=(g8&63)*8;
  size_t o = (size_t)row*DI + cb;
  float Cv = dbc[(size_t)row*18+17];
  int4 xi = *(const int4*)(xi_b+o);
  int4 sz = *(const int4*)(sz_b+o);
  int4 hh = *(const int4*)(h+o);
  int   xw[4] = {xi.x,xi.y,xi.z,xi.w};
  int   sw[4] = {sz.x,sz.y,sz.z,sz.w};
  int   hw[4] = {hh.x,hh.y,hh.z,hh.w};
  unsigned ov[4];
  #pragma unroll
  for (int q=0;q<4;q++){
    float xlo=b2f((unsigned short)((unsigned)xw[q]&0xFFFFu)), xhi=b2f((unsigned short)((unsigned)xw[q]>>16));
    float slo=b2f((unsigned short)((unsigned)sw[q]&0xFFFFu)), shi=b2f((unsigned short)((unsigned)sw[q]>>16));
    float hlo=b2f((unsigned short)((unsigned)hw[q]&0xFFFFu)), hhi=b2f((unsigned short)((unsigned)hw[q]>>16));
    float ylo=(Cv*hlo + Dp[cb+2*q+0]*xlo)*slo;
    float yhi=(Cv*hhi + Dp[cb+2*q+1]*xhi)*shi;
    ov[q] = (unsigned)f2b(ylo) | ((unsigned)f2b(yhi)<<16);
  }
  int4 outv; outv.x=(int)ov[0]; outv.y=(int)ov[1]; outv.z=(int)ov[2]; outv.w=(int)ov[3];
  *(int4*)(u_b+o) = outv;
}

// ---------------- launch ----------------
extern "C" void kernel_launch(void* const* d_in, const int* in_sizes, int n_in,
                              void* d_out, int out_size, void* d_ws, size_t ws_size,
                              hipStream_t stream) {
  (void)in_sizes; (void)n_in; (void)out_size; (void)ws_size;
  const float* x      = (const float*)d_in[0];
  const float* n1w    = (const float*)d_in[1];
  const float* n1b    = (const float*)d_in[2];
  const float* n2w    = (const float*)d_in[3];
  const float* n2b    = (const float*)d_in[4];
  const float* W_in   = (const float*)d_in[5];
  const float* b_in   = (const float*)d_in[6];
  const float* W_xp   = (const float*)d_in[7];
  const float* W_dt   = (const float*)d_in[8];
  const float* b_dt   = (const float*)d_in[9];
  const float* A_log  = (const float*)d_in[10];
  const float* Dp     = (const float*)d_in[11];
  const float* W_out  = (const float*)d_in[12];
  const float* b_out  = (const float*)d_in[13];
  const float* fc1_w  = (const float*)d_in[14];
  const float* fc1_b  = (const float*)d_in[15];
  const float* fc2_w  = (const float*)d_in[16];
  const float* fc2_b  = (const float*)d_in[17];

  char* base=(char*)d_ws; size_t off=0;
  auto alc=[&](size_t nb)->char*{ char* p=base+off; off=(off+nb+255)&~(size_t)255; return p; };
  float* wgt            = (float*)alc((size_t)MM*4*4);
  float* innorm         = (float*)alc((size_t)MM*4);
  int* par_g            = (int*)alc((size_t)MM*4);
  int* lvlorder         = (int*)alc((size_t)MM*4);
  int* lvlstart         = (int*)alc((size_t)BB*(NN+2)*4);
  int* nlvl             = (int*)alc((size_t)BB*4);
  unsigned short* xi_b  = (unsigned short*)alc((size_t)MM*DI*2);
  unsigned short* sz_b  = (unsigned short*)alc((size_t)MM*DI*2);   // contiguous after xi_b
  float* dbc            = (float*)alc((size_t)MM*18*4);
  unsigned short* dec_b = (unsigned short*)alc((size_t)MM*DI*2);
  unsigned short* bxh_b = (unsigned short*)alc((size_t)MM*DI*2);
  unsigned short* WinT  = (unsigned short*)alc((size_t)CC*1024*2);
  unsigned short* WoutT = (unsigned short*)alc((size_t)DI*CC*2);
  unsigned short* fc1T  = (unsigned short*)alc((size_t)CC*1024*2);
  unsigned short* fc2T  = (unsigned short*)alc((size_t)1024*CC*2);
  float* WxpT           = (float*)alc((size_t)DI*18*4);
  // lifetime-based aliases (linear allocator total ~157 MB):
  unsigned short* xn    = (unsigned short*)dec_b;   // [MM][256] bf16; dead before k_dbx writes dec_b
  unsigned short* u_b   = sz_b;                     // in-place over sz (same-element read->write)
  float* x2             = (float*)dec_b;            // [MM][256] f32; dec dead after scan
  unsigned short* x2n   = bxh_b;                    // [MM][256] bf16; h dead after k_u
  unsigned short* g1_b  = xi_b;                     // [MM][1024] bf16; spans xi_b+sz_b, both dead

  k_wconv<<<dim3((256*1024+255)/256),dim3(256),0,stream>>>(W_in, WinT, 256,1024);
  k_wconv<<<dim3((512*256 +255)/256),dim3(256),0,stream>>>(W_out, WoutT, 512,256);
  k_wconv<<<dim3((256*1024+255)/256),dim3(256),0,stream>>>(fc1_w, fc1T, 256,1024);
  k_wconv<<<dim3((1024*256+255)/256),dim3(256),0,stream>>>(fc2_w, fc2T, 1024,256);
  k_t32  <<<dim3((512*18  +255)/256),dim3(256),0,stream>>>(W_xp, WxpT, 512,18);

  k_norm<<<dim3(MM/4),dim3(256),0,stream>>>(x, innorm);
  k_edge<<<dim3(MM/4),dim3(256),0,stream>>>(x, innorm, wgt);
  k_prim<<<dim3(BB),dim3(64),0,stream>>>(wgt, par_g, lvlorder, lvlstart, nlvl);

  k_ln<<<dim3(MM/4),dim3(256),0,stream>>>(x, n1w, n1b, xn);
  k_gemm<0><<<dim3(288*8),dim3(256),0,stream>>>(xn, WinT, b_in, 1024, 256, nullptr, nullptr, xi_b, sz_b);
  k_dbc<<<dim3(MM/4),dim3(256),0,stream>>>(xi_b, WxpT, dbc);
  k_dbx<<<dim3(MM),dim3(512),0,stream>>>(dbc, xi_b, W_dt, b_dt, A_log, dec_b, bxh_b);
  k_scan<<<dim3(BB),dim3(1024),0,stream>>>(dec_b, bxh_b, par_g, lvlorder, lvlstart, nlvl);
  k_u<<<dim3(MM*64/256),dim3(256),0,stream>>>(bxh_b, xi_b, sz_b, dbc, Dp, u_b);
  k_gemm<1><<<dim3(288*2),dim3(256),0,stream>>>(u_b, WoutT, b_out, 256, 512, x, x2, nullptr, nullptr);

  k_ln<<<dim3(MM/4),dim3(256),0,stream>>>(x2, n2w, n2b, x2n);
  k_gemm<2><<<dim3(288*8),dim3(256),0,stream>>>(x2n, fc1T, fc1_b, 1024, 256, nullptr, nullptr, g1_b, nullptr);
  k_gemm<1><<<dim3(288*2),dim3(256),0,stream>>>(g1_b, fc2T, fc2_b, 256, 1024, x2, (float*)d_out, nullptr, nullptr);
}

// Round 3
// 2999.919 us; speedup vs baseline: 1.2544x; 1.2544x over previous
//
#include <hip/hip_runtime.h>
#include <math.h>

#define NN 2304
#define BB 16
#define CC 256
#define DI 512
#define MM (BB*NN)   // 36864

typedef __attribute__((ext_vector_type(8))) short bf16x8;
typedef __attribute__((ext_vector_type(4))) float f32x4;

__device__ inline unsigned short f2b(float f){
  unsigned u = __float_as_uint(f);
  u = u + 0x7FFFu + ((u>>16)&1u);
  return (unsigned short)(u>>16);
}
__device__ inline float b2f(unsigned short s){ return __uint_as_float(((unsigned)s)<<16); }

// ---------------- weight convert / transpose ----------------
__global__ __launch_bounds__(256) void k_wconv(const float* __restrict__ in, unsigned short* __restrict__ out, int R, int Ccols){
  int idx = blockIdx.x*256 + threadIdx.x;
  if (idx >= R*Ccols) return;
  int r = idx / Ccols, c = idx - r*Ccols;
  out[(size_t)c*R + r] = f2b(in[idx]);
}
__global__ __launch_bounds__(256) void k_t32(const float* __restrict__ in, float* __restrict__ out, int R, int Ccols){
  int idx = blockIdx.x*256 + threadIdx.x;
  if (idx >= R*Ccols) return;
  int r = idx / Ccols, c = idx - r*Ccols;
  out[(size_t)c*R + r] = in[idx];
}

// ---------------- feature norms ----------------
__global__ __launch_bounds__(256) void k_norm(const float* __restrict__ x, float* __restrict__ innorm){
  int row = blockIdx.x*4 + (threadIdx.x>>6); int lane = threadIdx.x&63;
  float4 v = *(const float4*)(x + (size_t)row*CC + lane*4);
  float s = v.x*v.x + v.y*v.y + v.z*v.z + v.w*v.w;
  #pragma unroll
  for (int o=32;o;o>>=1) s += __shfl_xor(s,o);
  if (lane==0) innorm[row] = 1.0f/(sqrtf(s)+1e-8f);
}

// ---------------- edge weights exp(1-cos) ----------------
__global__ __launch_bounds__(256) void k_edge(const float* __restrict__ x, const float* __restrict__ innorm, float* __restrict__ wgt){
  int g = blockIdx.x*4 + (threadIdx.x>>6); int lane = threadIdx.x&63;
  int b = g/NN, n = g - b*NN;
  int r = n/48, c = n - (n/48)*48;
  const float* xb = x + ((size_t)b*NN)*CC;
  float4 vu = *(const float4*)(xb + (size_t)n*CC + lane*4);
  int nb0=(r>0)?n-48:-1, nb1=(r<47)?n+48:-1, nb2=(c>0)?n-1:-1, nb3=(c<47)?n+1:-1;
  float d0=0,d1=0,d2=0,d3=0;
  if (nb0>=0){ float4 t=*(const float4*)(xb+(size_t)nb0*CC+lane*4); d0=vu.x*t.x+vu.y*t.y+vu.z*t.z+vu.w*t.w; }
  if (nb1>=0){ float4 t=*(const float4*)(xb+(size_t)nb1*CC+lane*4); d1=vu.x*t.x+vu.y*t.y+vu.z*t.z+vu.w*t.w; }
  if (nb2>=0){ float4 t=*(const float4*)(xb+(size_t)nb2*CC+lane*4); d2=vu.x*t.x+vu.y*t.y+vu.z*t.z+vu.w*t.w; }
  if (nb3>=0){ float4 t=*(const float4*)(xb+(size_t)nb3*CC+lane*4); d3=vu.x*t.x+vu.y*t.y+vu.z*t.z+vu.w*t.w; }
  #pragma unroll
  for (int o=32;o;o>>=1){ d0+=__shfl_xor(d0,o); d1+=__shfl_xor(d1,o); d2+=__shfl_xor(d2,o); d3+=__shfl_xor(d3,o); }
  if (lane==0){
    float inu = innorm[g];
    float inf_ = __uint_as_float(0x7F800000u);
    float4 w;
    w.x = (nb0>=0)? expf(1.0f - d0*(inu*innorm[g-n+nb0])) : inf_;
    w.y = (nb1>=0)? expf(1.0f - d1*(inu*innorm[g-n+nb1])) : inf_;
    w.z = (nb2>=0)? expf(1.0f - d2*(inu*innorm[g-n+nb2])) : inf_;
    w.w = (nb3>=0)? expf(1.0f - d3*(inu*innorm[g-n+nb3])) : inf_;
    *(float4*)(wgt + (size_t)g*4) = w;
  }
}

// ---------------- Prim MST: 32-bit keys, 1 reduce + 1 barrier per step ----------------
// Tie-break matches jnp.argmin (first index): within a lane's segment the select
// chain keeps the first (smallest local idx); across lanes the lowest lane with
// the min value wins (segments are index-ordered), picked via ballot+ffs.
__global__ __launch_bounds__(64) void k_prim(const float* __restrict__ wgt, int* __restrict__ par_g,
      int* __restrict__ lvlorder, int* __restrict__ lvlstart, int* __restrict__ nlvl)
{
  __shared__ float keyf[NN];
  __shared__ float wls[NN*4];         // aliased as hist[] after the main loop
  __shared__ unsigned short par[NN];
  __shared__ unsigned short dep[NN];  // 0xFFFF = not in tree
  int b = blockIdx.x, lane = threadIdx.x;
  const float FINF = __uint_as_float(0x7F800000u);
  {
    const float4* wg4 = (const float4*)(wgt + (size_t)b*NN*4);
    float4* wl4 = (float4*)wls;
    for (int i=lane;i<NN;i+=64){
      wl4[i] = wg4[i];
      keyf[i] = (i==0) ? 0.f : FINF;
      par[i]=0; dep[i]=0xFFFFu;
    }
  }
  __syncthreads();
  int maxd=0;  // live on lane 5
  const int sb = lane*36;
  for (int step=0; step<NN; step++){
    // ---- segment scan (own 36 keys, 9x ds_read_b128) ----
    float mn=FINF; int mi=0;
    #pragma unroll
    for (int q=0;q<9;q++){
      float4 v = *(const float4*)&keyf[sb+q*4];
      if (v.x<mn){mn=v.x;mi=q*4+0;}
      if (v.y<mn){mn=v.y;mi=q*4+1;}
      if (v.z<mn){mn=v.z;mi=q*4+2;}
      if (v.w<mn){mn=v.w;mi=q*4+3;}
    }
    // ---- 32-bit butterfly min + ballot tie-break ----
    float bm=mn;
    #pragma unroll
    for (int o=32;o;o>>=1){ float t=__shfl_xor(bm,o); bm=fminf(bm,t); }
    unsigned long long msk = __ballot(mn==bm);
    int fl = __ffsll((unsigned long long)msk) - 1;
    int u = __shfl(sb+mi, fl);
    // ---- updates (lanes 0-5), visible after the single barrier ----
    int r = u/48, c = u - (u/48)*48;
    if (lane < 6){
      if (lane < 4){
        int nb;
        if      (lane==0) nb = (r>0)  ? u-48 : -1;
        else if (lane==1) nb = (r<47) ? u+48 : -1;
        else if (lane==2) nb = (c>0)  ? u-1  : -1;
        else              nb = (c<47) ? u+1  : -1;
        if (nb>=0 && dep[nb]==0xFFFFu){
          float wv = wls[u*4+lane];
          if (wv < keyf[nb]){ keyf[nb]=wv; par[nb]=(unsigned short)u; }
        }
      } else if (lane==4){
        keyf[u] = FINF;
      } else {
        int du = (step==0) ? 0 : ((int)dep[par[u]] + 1);
        dep[u] = (unsigned short)du;
        if (du>maxd) maxd=du;
      }
    }
    __syncthreads();
  }
  maxd = __shfl(maxd, 5);
  int nlv = maxd+1;
  int* hist = (int*)wls;              // wls dead now
  for (int i=lane;i<=nlv;i+=64) hist[i]=0;
  __syncthreads();
  for (int j=0;j<36;j++) atomicAdd(&hist[dep[sb+j]],1);
  __syncthreads();
  if (lane==0){
    int run=0;
    for (int l=0;l<nlv;l++){ int cnt=hist[l]; hist[l]=run; lvlstart[b*(NN+2)+l]=run; run+=cnt; }
    lvlstart[b*(NN+2)+nlv]=run;
    nlvl[b]=nlv;
  }
  __syncthreads();
  for (int j=0;j<36;j++){
    int i=sb+j;
    int pos=atomicAdd(&hist[dep[i]],1);
    lvlorder[b*NN+pos]=i;
  }
  for (int i=lane;i<NN;i+=64) par_g[b*NN+i]=(int)par[i];
}

// ---------------- LayerNorm -> bf16 ----------------
__global__ __launch_bounds__(256) void k_ln(const float* __restrict__ xin, const float* __restrict__ g,
    const float* __restrict__ bta, unsigned short* __restrict__ outb)
{
  int row = blockIdx.x*4 + (threadIdx.x>>6); int lane=threadIdx.x&63;
  float4 v = *(const float4*)(xin + (size_t)row*CC + lane*4);
  float s = v.x+v.y+v.z+v.w;
  #pragma unroll
  for (int o=32;o;o>>=1) s += __shfl_xor(s,o);
  float m = s*(1.0f/256.0f);
  float dx=v.x-m, dy=v.y-m, dz=v.z-m, dw=v.w-m;
  float ss=dx*dx+dy*dy+dz*dz+dw*dw;
  #pragma unroll
  for (int o=32;o;o>>=1) ss += __shfl_xor(ss,o);
  float rs = rsqrtf(ss*(1.0f/256.0f)+1e-5f);
  int cb=lane*4;
  unsigned o0 = (unsigned)f2b(dx*rs*g[cb+0]+bta[cb+0]) | ((unsigned)f2b(dy*rs*g[cb+1]+bta[cb+1])<<16);
  unsigned o1 = (unsigned)f2b(dz*rs*g[cb+2]+bta[cb+2]) | ((unsigned)f2b(dw*rs*g[cb+3]+bta[cb+3])<<16);
  *(uint2*)(outb + (size_t)row*CC + cb) = make_uint2(o0,o1);
}

// ---------------- bf16 MFMA GEMM, 128x128 tile, fused epilogues ----------------
template<int EPI>
__global__ __launch_bounds__(256) void k_gemm(
    const unsigned short* __restrict__ A, const unsigned short* __restrict__ BT,
    const float* __restrict__ bias, int Ndim, int K,
    const float* __restrict__ addin, float* __restrict__ fout,
    unsigned short* __restrict__ bout0, unsigned short* __restrict__ bout1)
{
  __shared__ __align__(16) unsigned short lA[128*32];
  __shared__ __align__(16) unsigned short lB[128*32];
  int tid=threadIdx.x, wid=tid>>6, lane=tid&63;
  int ntn = Ndim>>7;
  int bm = blockIdx.x/ntn, bn = blockIdx.x - bm*ntn;
  const unsigned short* Ab = A + (size_t)bm*128*K;
  const unsigned short* Bb = BT + (size_t)bn*128*K;
  int wr=wid>>1, wc=wid&1;
  f32x4 acc[4][4];
  #pragma unroll
  for (int m2=0;m2<4;m2++)
    #pragma unroll
    for (int n2=0;n2<4;n2++)
      #pragma unroll
      for (int j=0;j<4;j++) acc[m2][n2][j]=0.f;
  int r0 = tid>>2, c0 = (tid&3)*8;
  for (int k0=0;k0<K;k0+=32){
    int4 va0 = *(const int4*)(Ab + (size_t)r0*K + k0 + c0);
    int4 va1 = *(const int4*)(Ab + (size_t)(r0+64)*K + k0 + c0);
    int4 vb0 = *(const int4*)(Bb + (size_t)r0*K + k0 + c0);
    int4 vb1 = *(const int4*)(Bb + (size_t)(r0+64)*K + k0 + c0);
    __syncthreads();
    *(int4*)(lA + r0*32 + c0) = va0;
    *(int4*)(lA + (r0+64)*32 + c0) = va1;
    *(int4*)(lB + r0*32 + c0) = vb0;
    *(int4*)(lB + (r0+64)*32 + c0) = vb1;
    __syncthreads();
    int ra = (wr<<6) + (lane&15);
    int rb = (wc<<6) + (lane&15);
    int cb = (lane>>4)<<3;
    bf16x8 af[4], bfr[4];
    #pragma unroll
    for (int m2=0;m2<4;m2++) af[m2] = *(const bf16x8*)(lA + (ra+m2*16)*32 + cb);
    #pragma unroll
    for (int n2=0;n2<4;n2++) bfr[n2] = *(const bf16x8*)(lB + (rb+n2*16)*32 + cb);
    #pragma unroll
    for (int m2=0;m2<4;m2++)
      #pragma unroll
      for (int n2=0;n2<4;n2++)
        acc[m2][n2] = __builtin_amdgcn_mfma_f32_16x16x32_bf16(af[m2], bfr[n2], acc[m2][n2], 0,0,0);
  }
  int rr = (lane>>4)<<2, cc = lane&15;
  #pragma unroll
  for (int m2=0;m2<4;m2++){
    #pragma unroll
    for (int n2=0;n2<4;n2++){
      int col = (bn<<7) + (wc<<6) + (n2<<4) + cc;
      float bs = bias[col];
      #pragma unroll
      for (int j=0;j<4;j++){
        int row = (bm<<7) + (wr<<6) + (m2<<4) + rr + j;
        float v = acc[m2][n2][j] + bs;
        if (EPI==0){
          float sv = v * (1.0f/(1.0f+expf(-v)));
          if (col < DI) bout0[(size_t)row*DI + col] = f2b(sv);
          else          bout1[(size_t)row*DI + col - DI] = f2b(sv);
        } else if (EPI==1){
          size_t oi=(size_t)row*Ndim+col;
          fout[oi] = addin[oi] + v;
        } else {
          size_t oi=(size_t)row*Ndim+col;
          bout0[oi] = f2b(0.5f*v*(1.0f+erff(v*0.70710678118f)));
        }
      }
    }
  }
}

// ---------------- dbc = xi @ W_xp  (18 cols) ----------------
__global__ __launch_bounds__(256) void k_dbc(const unsigned short* __restrict__ xi_b,
    const float* __restrict__ WxpT, float* __restrict__ dbc)
{
  int row = blockIdx.x*4 + (threadIdx.x>>6); int lane=threadIdx.x&63;
  int4 raw = *(const int4*)(xi_b + (size_t)row*DI + lane*8);
  float xf[8];
  xf[0]=b2f((unsigned short)((unsigned)raw.x&0xFFFFu)); xf[1]=b2f((unsigned short)((unsigned)raw.x>>16));
  xf[2]=b2f((unsigned short)((unsigned)raw.y&0xFFFFu)); xf[3]=b2f((unsigned short)((unsigned)raw.y>>16));
  xf[4]=b2f((unsigned short)((unsigned)raw.z&0xFFFFu)); xf[5]=b2f((unsigned short)((unsigned)raw.z>>16));
  xf[6]=b2f((unsigned short)((unsigned)raw.w&0xFFFFu)); xf[7]=b2f((unsigned short)((unsigned)raw.w>>16));
  for (int jc=0;jc<18;jc++){
    const float* wr_ = WxpT + (size_t)jc*DI + lane*8;
    float s=0.f;
    #pragma unroll
    for (int t=0;t<8;t++) s += xf[t]*wr_[t];
    #pragma unroll
    for (int o=32;o;o>>=1) s += __shfl_xor(s,o);
    if (lane==0) dbc[(size_t)row*18+jc]=s;
  }
}

// ---------------- dt/softplus -> decay (bf16), Bx (bf16) ----------------
__global__ __launch_bounds__(512) void k_dbx(const float* __restrict__ dbc, const unsigned short* __restrict__ xi_b,
  const float* __restrict__ W_dt, const float* __restrict__ b_dt, const float* __restrict__ A_log,
  unsigned short* __restrict__ decay, unsigned short* __restrict__ Bx)
{
  int row=blockIdx.x, c=threadIdx.x;
  __shared__ float sd[18];
  if (c<18) sd[c]=dbc[(size_t)row*18+c];
  __syncthreads();
  float a=b_dt[c];
  #pragma unroll
  for (int r2=0;r2<16;r2++) a += sd[r2]*W_dt[r2*DI+c];
  float dt = (a>20.f)? a : log1pf(expf(a));
  size_t o=(size_t)row*DI+c;
  decay[o]=f2b(expf(dt * -expf(A_log[c])));
  Bx[o]=f2b(dt*sd[16]*b2f(xi_b[o]));
}

// ---------------- level-parallel tree scan, 4 channels/block in LDS ----------------
#define SCH 4
__global__ __launch_bounds__(256) void k_scan(const unsigned short* __restrict__ decay,
    unsigned short* __restrict__ bxh,
    const int* __restrict__ par_g, const int* __restrict__ lvlorder, const int* __restrict__ lvlstart,
    const int* __restrict__ nlvl)
{
  __shared__ unsigned short sdec[NN*SCH];
  __shared__ unsigned short sbx[NN*SCH];
  __shared__ int sord[NN];
  __shared__ unsigned short spar[NN];
  int b = blockIdx.x>>7, t = blockIdx.x&127;
  int c0 = t*SCH;
  int tid = threadIdx.x;
  const size_t gbase = (size_t)b*NN*DI;
  for (int i=tid; i<NN*2; i+=256){
    int node=i>>1, p=i&1;
    size_t go = gbase + (size_t)node*DI + c0 + p*2;
    *(unsigned*)&sdec[node*SCH+p*2] = *(const unsigned*)&decay[go];
    *(unsigned*)&sbx [node*SCH+p*2] = *(const unsigned*)&bxh[go];
  }
  for (int i=tid;i<NN;i+=256){ sord[i]=lvlorder[b*NN+i]; spar[i]=(unsigned short)par_g[b*NN+i]; }
  int nlv = nlvl[b];
  __syncthreads();
  for (int lvl=1; lvl<nlv; lvl++){
    int s=lvlstart[b*(NN+2)+lvl], e=lvlstart[b*(NN+2)+lvl+1];
    int tot=(e-s)*SCH;
    for (int idx=tid; idx<tot; idx+=256){
      int node = sord[s + (idx>>2)];
      int cc = idx&3;
      int pv = spar[node];
      float hv = b2f(sdec[node*SCH+cc])*b2f(sbx[pv*SCH+cc]) + b2f(sbx[node*SCH+cc]);
      sbx[node*SCH+cc] = f2b(hv);
    }
    __syncthreads();
  }
  for (int i=tid; i<NN*2; i+=256){
    int node=i>>1, p=i&1;
    size_t go = gbase + (size_t)node*DI + c0 + p*2;
    *(unsigned*)&bxh[go] = *(const unsigned*)&sbx[node*SCH+p*2];
  }
}

// ---------------- u = (Cv*h + Dp*xi) * silu(z) -> bf16 (in place over sz) ----------------
__global__ __launch_bounds__(256) void k_u(const unsigned short* __restrict__ h, const unsigned short* __restrict__ xi_b,
    const unsigned short* __restrict__ sz_b, const float* __restrict__ dbc, const float* __restrict__ Dp,
    unsigned short* __restrict__ u_b)
{
  int g8 = blockIdx.x*256 + threadIdx.x;
  int row = g8>>6; int cb=(g8&63)*8;
  size_t o = (size_t)row*DI + cb;
  float Cv = dbc[(size_t)row*18+17];
  int4 xi = *(const int4*)(xi_b+o);
  int4 sz = *(const int4*)(sz_b+o);
  int4 hh = *(const int4*)(h+o);
  int   xw[4] = {xi.x,xi.y,xi.z,xi.w};
  int   sw[4] = {sz.x,sz.y,sz.z,sz.w};
  int   hw[4] = {hh.x,hh.y,hh.z,hh.w};
  unsigned ov[4];
  #pragma unroll
  for (int q=0;q<4;q++){
    float xlo=b2f((unsigned short)((unsigned)xw[q]&0xFFFFu)), xhi=b2f((unsigned short)((unsigned)xw[q]>>16));
    float slo=b2f((unsigned short)((unsigned)sw[q]&0xFFFFu)), shi=b2f((unsigned short)((unsigned)sw[q]>>16));
    float hlo=b2f((unsigned short)((unsigned)hw[q]&0xFFFFu)), hhi=b2f((unsigned short)((unsigned)hw[q]>>16));
    float ylo=(Cv*hlo + Dp[cb+2*q+0]*xlo)*slo;
    float yhi=(Cv*hhi + Dp[cb+2*q+1]*xhi)*shi;
    ov[q] = (unsigned)f2b(ylo) | ((unsigned)f2b(yhi)<<16);
  }
  int4 outv; outv.x=(int)ov[0]; outv.y=(int)ov[1]; outv.z=(int)ov[2]; outv.w=(int)ov[3];
  *(int4*)(u_b+o) = outv;
}

// ---------------- launch ----------------
extern "C" void kernel_launch(void* const* d_in, const int* in_sizes, int n_in,
                              void* d_out, int out_size, void* d_ws, size_t ws_size,
                              hipStream_t stream) {
  (void)in_sizes; (void)n_in; (void)out_size; (void)ws_size;
  const float* x      = (const float*)d_in[0];
  const float* n1w    = (const float*)d_in[1];
  const float* n1b    = (const float*)d_in[2];
  const float* n2w    = (const float*)d_in[3];
  const float* n2b    = (const float*)d_in[4];
  const float* W_in   = (const float*)d_in[5];
  const float* b_in   = (const float*)d_in[6];
  const float* W_xp   = (const float*)d_in[7];
  const float* W_dt   = (const float*)d_in[8];
  const float* b_dt   = (const float*)d_in[9];
  const float* A_log  = (const float*)d_in[10];
  const float* Dp     = (const float*)d_in[11];
  const float* W_out  = (const float*)d_in[12];
  const float* b_out  = (const float*)d_in[13];
  const float* fc1_w  = (const float*)d_in[14];
  const float* fc1_b  = (const float*)d_in[15];
  const float* fc2_w  = (const float*)d_in[16];
  const float* fc2_b  = (const float*)d_in[17];

  char* base=(char*)d_ws; size_t off=0;
  auto alc=[&](size_t nb)->char*{ char* p=base+off; off=(off+nb+255)&~(size_t)255; return p; };
  float* wgt            = (float*)alc((size_t)MM*4*4);
  float* innorm         = (float*)alc((size_t)MM*4);
  int* par_g            = (int*)alc((size_t)MM*4);
  int* lvlorder         = (int*)alc((size_t)MM*4);
  int* lvlstart         = (int*)alc((size_t)BB*(NN+2)*4);
  int* nlvl             = (int*)alc((size_t)BB*4);
  unsigned short* xi_b  = (unsigned short*)alc((size_t)MM*DI*2);
  unsigned short* sz_b  = (unsigned short*)alc((size_t)MM*DI*2);   // contiguous after xi_b
  float* dbc            = (float*)alc((size_t)MM*18*4);
  unsigned short* dec_b = (unsigned short*)alc((size_t)MM*DI*2);
  unsigned short* bxh_b = (unsigned short*)alc((size_t)MM*DI*2);
  unsigned short* WinT  = (unsigned short*)alc((size_t)CC*1024*2);
  unsigned short* WoutT = (unsigned short*)alc((size_t)DI*CC*2);
  unsigned short* fc1T  = (unsigned short*)alc((size_t)CC*1024*2);
  unsigned short* fc2T  = (unsigned short*)alc((size_t)1024*CC*2);
  float* WxpT           = (float*)alc((size_t)DI*18*4);
  // lifetime-based aliases:
  unsigned short* xn    = (unsigned short*)dec_b;   // [MM][256] bf16; dead before k_dbx writes dec_b
  unsigned short* u_b   = sz_b;                     // in-place over sz
  float* x2             = (float*)dec_b;            // [MM][256] f32; dec dead after scan
  unsigned short* x2n   = bxh_b;                    // [MM][256] bf16; h dead after k_u
  unsigned short* g1_b  = xi_b;                     // [MM][1024] bf16; spans xi_b+sz_b

  k_wconv<<<dim3((256*1024+255)/256),dim3(256),0,stream>>>(W_in, WinT, 256,1024);
  k_wconv<<<dim3((512*256 +255)/256),dim3(256),0,stream>>>(W_out, WoutT, 512,256);
  k_wconv<<<dim3((256*1024+255)/256),dim3(256),0,stream>>>(fc1_w, fc1T, 256,1024);
  k_wconv<<<dim3((1024*256+255)/256),dim3(256),0,stream>>>(fc2_w, fc2T, 1024,256);
  k_t32  <<<dim3((512*18  +255)/256),dim3(256),0,stream>>>(W_xp, WxpT, 512,18);

  k_norm<<<dim3(MM/4),dim3(256),0,stream>>>(x, innorm);
  k_edge<<<dim3(MM/4),dim3(256),0,stream>>>(x, innorm, wgt);
  k_prim<<<dim3(BB),dim3(64),0,stream>>>(wgt, par_g, lvlorder, lvlstart, nlvl);

  k_ln<<<dim3(MM/4),dim3(256),0,stream>>>(x, n1w, n1b, xn);
  k_gemm<0><<<dim3(288*8),dim3(256),0,stream>>>(xn, WinT, b_in, 1024, 256, nullptr, nullptr, xi_b, sz_b);
  k_dbc<<<dim3(MM/4),dim3(256),0,stream>>>(xi_b, WxpT, dbc);
  k_dbx<<<dim3(MM),dim3(512),0,stream>>>(dbc, xi_b, W_dt, b_dt, A_log, dec_b, bxh_b);
  k_scan<<<dim3(BB*128),dim3(256),0,stream>>>(dec_b, bxh_b, par_g, lvlorder, lvlstart, nlvl);
  k_u<<<dim3(MM*64/256),dim3(256),0,stream>>>(bxh_b, xi_b, sz_b, dbc, Dp, u_b);
  k_gemm<1><<<dim3(288*2),dim3(256),0,stream>>>(u_b, WoutT, b_out, 256, 512, x, x2, nullptr, nullptr);

  k_ln<<<dim3(MM/4),dim3(256),0,stream>>>(x2, n2w, n2b, x2n);
  k_gemm<2><<<dim3(288*8),dim3(256),0,stream>>>(x2n, fc1T, fc1_b, 1024, 256, nullptr, nullptr, g1_b, nullptr);
  k_gemm<1><<<dim3(288*2),dim3(256),0,stream>>>(g1_b, fc2T, fc2_b, 256, 1024, x2, (float*)d_out, nullptr, nullptr);
}

// Round 4
// 2207.883 us; speedup vs baseline: 1.7044x; 1.3587x over previous
//
#include <hip/hip_runtime.h>
#include <math.h>

#define NN 2304
#define BB 16
#define CC 256
#define DI 512
#define MM (BB*NN)   // 36864

typedef __attribute__((ext_vector_type(8))) short bf16x8;
typedef __attribute__((ext_vector_type(4))) float f32x4;

__device__ inline unsigned short f2b(float f){
  unsigned u = __float_as_uint(f);
  u = u + 0x7FFFu + ((u>>16)&1u);
  return (unsigned short)(u>>16);
}
__device__ inline float b2f(unsigned short s){ return __uint_as_float(((unsigned)s)<<16); }

// 64-lane unsigned-min reduce via DPP (VALU latency, no LDS). Result broadcast via readlane.
__device__ __forceinline__ unsigned umin_dpp64(unsigned x){
  unsigned t;
  t = (unsigned)__builtin_amdgcn_update_dpp((int)x,(int)x,0x111,0xF,0xF,false); x = t<x?t:x; // row_shr:1
  t = (unsigned)__builtin_amdgcn_update_dpp((int)x,(int)x,0x112,0xF,0xF,false); x = t<x?t:x; // row_shr:2
  t = (unsigned)__builtin_amdgcn_update_dpp((int)x,(int)x,0x114,0xF,0xF,false); x = t<x?t:x; // row_shr:4
  t = (unsigned)__builtin_amdgcn_update_dpp((int)x,(int)x,0x118,0xF,0xF,false); x = t<x?t:x; // row_shr:8
  t = (unsigned)__builtin_amdgcn_update_dpp((int)x,(int)x,0x142,0xA,0xF,false); x = t<x?t:x; // row_bcast:15 -> rows 1,3
  t = (unsigned)__builtin_amdgcn_update_dpp((int)x,(int)x,0x143,0xC,0xF,false); x = t<x?t:x; // row_bcast:31 -> rows 2,3
  return (unsigned)__builtin_amdgcn_readlane((int)x, 63);
}

// ---------------- weight convert / transpose ----------------
__global__ __launch_bounds__(256) void k_wconv(const float* __restrict__ in, unsigned short* __restrict__ out, int R, int Ccols){
  int idx = blockIdx.x*256 + threadIdx.x;
  if (idx >= R*Ccols) return;
  int r = idx / Ccols, c = idx - r*Ccols;
  out[(size_t)c*R + r] = f2b(in[idx]);
}
__global__ __launch_bounds__(256) void k_t32(const float* __restrict__ in, float* __restrict__ out, int R, int Ccols){
  int idx = blockIdx.x*256 + threadIdx.x;
  if (idx >= R*Ccols) return;
  int r = idx / Ccols, c = idx - r*Ccols;
  out[(size_t)c*R + r] = in[idx];
}

// ---------------- feature norms ----------------
__global__ __launch_bounds__(256) void k_norm(const float* __restrict__ x, float* __restrict__ innorm){
  int row = blockIdx.x*4 + (threadIdx.x>>6); int lane = threadIdx.x&63;
  float4 v = *(const float4*)(x + (size_t)row*CC + lane*4);
  float s = v.x*v.x + v.y*v.y + v.z*v.z + v.w*v.w;
  #pragma unroll
  for (int o=32;o;o>>=1) s += __shfl_xor(s,o);
  if (lane==0) innorm[row] = 1.0f/(sqrtf(s)+1e-8f);
}

// ---------------- edge weights exp(1-cos) ----------------
__global__ __launch_bounds__(256) void k_edge(const float* __restrict__ x, const float* __restrict__ innorm, float* __restrict__ wgt){
  int g = blockIdx.x*4 + (threadIdx.x>>6); int lane = threadIdx.x&63;
  int b = g/NN, n = g - b*NN;
  int r = n/48, c = n - (n/48)*48;
  const float* xb = x + ((size_t)b*NN)*CC;
  float4 vu = *(const float4*)(xb + (size_t)n*CC + lane*4);
  int nb0=(r>0)?n-48:-1, nb1=(r<47)?n+48:-1, nb2=(c>0)?n-1:-1, nb3=(c<47)?n+1:-1;
  float d0=0,d1=0,d2=0,d3=0;
  if (nb0>=0){ float4 t=*(const float4*)(xb+(size_t)nb0*CC+lane*4); d0=vu.x*t.x+vu.y*t.y+vu.z*t.z+vu.w*t.w; }
  if (nb1>=0){ float4 t=*(const float4*)(xb+(size_t)nb1*CC+lane*4); d1=vu.x*t.x+vu.y*t.y+vu.z*t.z+vu.w*t.w; }
  if (nb2>=0){ float4 t=*(const float4*)(xb+(size_t)nb2*CC+lane*4); d2=vu.x*t.x+vu.y*t.y+vu.z*t.z+vu.w*t.w; }
  if (nb3>=0){ float4 t=*(const float4*)(xb+(size_t)nb3*CC+lane*4); d3=vu.x*t.x+vu.y*t.y+vu.z*t.z+vu.w*t.w; }
  #pragma unroll
  for (int o=32;o;o>>=1){ d0+=__shfl_xor(d0,o); d1+=__shfl_xor(d1,o); d2+=__shfl_xor(d2,o); d3+=__shfl_xor(d3,o); }
  if (lane==0){
    float inu = innorm[g];
    float inf_ = __uint_as_float(0x7F800000u);
    float4 w;
    w.x = (nb0>=0)? expf(1.0f - d0*(inu*innorm[g-n+nb0])) : inf_;
    w.y = (nb1>=0)? expf(1.0f - d1*(inu*innorm[g-n+nb1])) : inf_;
    w.z = (nb2>=0)? expf(1.0f - d2*(inu*innorm[g-n+nb2])) : inf_;
    w.w = (nb3>=0)? expf(1.0f - d3*(inu*innorm[g-n+nb3])) : inf_;
    *(float4*)(wgt + (size_t)g*4) = w;
  }
}

// ---------------- Prim MST body: DPP reduce + incremental per-lane minima ----------------
// Single wave (lanes 0-63), zero barriers (per-wave in-order LDS).
// keyf: f32 keys, popped = -1.0f. parpd: (dep<<16)|par. Tie-break == jnp.argmin first-index:
// per-lane sidx = first index of lane's min; global: ballot lowest lane = lowest index.
__device__ void prim_body(unsigned char* smem, const float* __restrict__ wgt, int b,
    int* __restrict__ par_g, int* __restrict__ lvlorder, int* __restrict__ lvlstart, int* __restrict__ nlvl)
{
  float* keyf     = (float*)smem;                    //  9216 B
  float* wls      = (float*)(smem + 9216);           // 36864 B
  unsigned* parpd = (unsigned*)(smem + 9216 + 36864);//  9216 B
  const int lane = threadIdx.x;
  const unsigned INFB = 0x7F800000u;
  const float FINF = __uint_as_float(INFB);
  {
    const float4* wg4 = (const float4*)(wgt + (size_t)b*NN*4);
    float4* wl4 = (float4*)wls;
    for (int i=lane;i<NN;i+=64){ wl4[i]=wg4[i]; keyf[i]=(i==0)?0.f:FINF; parpd[i]=0u; }
  }
  unsigned sval = (lane==0)?0u:INFB;   // lane's segment-min (f32 bits; non-neg so uint order == float order)
  int sidx = lane*36;                  // first index achieving sval
  int maxd = 0;
  const int sb = lane*36;
  for (int step=0; step<NN; step++){
    // ---- global argmin: DPP min + ballot (first lane = first index) ----
    unsigned bm = umin_dpp64(sval);
    unsigned long long msk = __ballot(sval==bm);
    int fl = (int)(__ffsll(msk)-1);
    int u = __builtin_amdgcn_readlane(sidx, fl);
    int uo = u/36;
    int r = u/48, c = u - r*48;
    int nb0=(r>0)?u-48:-1, nb1=(r<47)?u+48:-1, nb2=(c>0)?u-1:-1, nb3=(c<47)?u+1:-1;
    // ---- broadcast LDS reads (pre-update state), all pipelined ----
    float4 w4 = *(const float4*)&wls[u*4];
    unsigned pdu = parpd[u];
    float k0 = keyf[nb0<0?0:nb0];
    float k1 = keyf[nb1<0?0:nb1];
    float k2 = keyf[nb2<0?0:nb2];
    float k3 = keyf[nb3<0?0:nb3];
    float cf = keyf[uo*36 + (lane<36?lane:0)];       // coop rescan read of owner's segment
    int ci = uo*36 + lane;
    unsigned rv = INFB;
    if (lane<36 && ci!=u && cf>=0.f) rv = __float_as_uint(cf);
    int du = (int)(pdu>>16);
    if (du>maxd) maxd=du;
    unsigned npd = ((unsigned)(du+1)<<16) | (unsigned)u;
    bool up0 = nb0>=0 && w4.x<k0;
    bool up1 = nb1>=0 && w4.y<k1;
    bool up2 = nb2>=0 && w4.z<k2;
    bool up3 = nb3>=0 && w4.w<k3;
    // ---- writes (visible next step; reads above already issued) ----
    if (lane==0){ if(up0){ keyf[nb0]=w4.x; parpd[nb0]=npd; } }
    else if (lane==1){ if(up1){ keyf[nb1]=w4.y; parpd[nb1]=npd; } }
    else if (lane==2){ if(up2){ keyf[nb2]=w4.z; parpd[nb2]=npd; } }
    else if (lane==3){ if(up3){ keyf[nb3]=w4.w; parpd[nb3]=npd; } }
    else if (lane==4){ keyf[u] = -1.0f; }
    // ---- owner rescan reduce (pre-update values), owner adopts ----
    unsigned m2 = umin_dpp64(rv);
    unsigned long long msk2 = __ballot(rv==m2);
    int l2 = (int)(__ffsll(msk2)-1);
    if (lane==uo){ sval = m2; sidx = uo*36 + l2; }
    // ---- fold this step's decreases into local minima (after owner adopt) ----
    if (up0 && nb0/36==lane){ unsigned wb=__float_as_uint(w4.x); if (wb<sval){sval=wb;sidx=nb0;} else if (wb==sval && nb0<sidx) sidx=nb0; }
    if (up1 && nb1/36==lane){ unsigned wb=__float_as_uint(w4.y); if (wb<sval){sval=wb;sidx=nb1;} else if (wb==sval && nb1<sidx) sidx=nb1; }
    if (up2 && nb2/36==lane){ unsigned wb=__float_as_uint(w4.z); if (wb<sval){sval=wb;sidx=nb2;} else if (wb==sval && nb2<sidx) sidx=nb2; }
    if (up3 && nb3/36==lane){ unsigned wb=__float_as_uint(w4.w); if (wb<sval){sval=wb;sidx=nb3;} else if (wb==sval && nb3<sidx) sidx=nb3; }
  }
  // ---- counting sort by depth -> lvlorder (valid topological order) ----
  int nlv = maxd+1;
  int* hist = (int*)wls;   // wls dead
  for (int i=lane;i<nlv;i+=64) hist[i]=0;
  for (int j=0;j<36;j++){ int d=(int)(parpd[sb+j]>>16); atomicAdd(&hist[d],1); }
  if (lane==0){
    int run=0;
    for (int l=0;l<nlv;l++){ int cnt=hist[l]; hist[l]=run; lvlstart[b*(NN+2)+l]=run; run+=cnt; }
    lvlstart[b*(NN+2)+nlv]=run;
    nlvl[b]=nlv;
  }
  for (int j=0;j<36;j++){
    int i=sb+j; int d=(int)(parpd[i]>>16);
    int pos=atomicAdd(&hist[d],1);
    lvlorder[b*NN+pos]=i;
  }
  for (int i=lane;i<NN;i+=64) par_g[b*NN+i]=(int)(parpd[i]&0xFFFFu);
}

// ---------------- bf16 MFMA GEMM body, 128x128 tile, fused epilogues ----------------
template<int EPI>
__device__ void gemm_body(unsigned short* lA, unsigned short* lB, int bm, int bn,
    const unsigned short* __restrict__ A, const unsigned short* __restrict__ BT,
    const float* __restrict__ bias, int Ndim, int K,
    const float* __restrict__ addin, float* __restrict__ fout,
    unsigned short* __restrict__ bout0, unsigned short* __restrict__ bout1)
{
  int tid=threadIdx.x, wid=tid>>6, lane=tid&63;
  const unsigned short* Ab = A + (size_t)bm*128*K;
  const unsigned short* Bb = BT + (size_t)bn*128*K;
  int wr=wid>>1, wc=wid&1;
  f32x4 acc[4][4];
  #pragma unroll
  for (int m2=0;m2<4;m2++)
    #pragma unroll
    for (int n2=0;n2<4;n2++)
      #pragma unroll
      for (int j=0;j<4;j++) acc[m2][n2][j]=0.f;
  int r0 = tid>>2, c0 = (tid&3)*8;
  for (int k0=0;k0<K;k0+=32){
    int4 va0 = *(const int4*)(Ab + (size_t)r0*K + k0 + c0);
    int4 va1 = *(const int4*)(Ab + (size_t)(r0+64)*K + k0 + c0);
    int4 vb0 = *(const int4*)(Bb + (size_t)r0*K + k0 + c0);
    int4 vb1 = *(const int4*)(Bb + (size_t)(r0+64)*K + k0 + c0);
    __syncthreads();
    *(int4*)(lA + r0*32 + c0) = va0;
    *(int4*)(lA + (r0+64)*32 + c0) = va1;
    *(int4*)(lB + r0*32 + c0) = vb0;
    *(int4*)(lB + (r0+64)*32 + c0) = vb1;
    __syncthreads();
    int ra = (wr<<6) + (lane&15);
    int rb = (wc<<6) + (lane&15);
    int cb = (lane>>4)<<3;
    bf16x8 af[4], bfr[4];
    #pragma unroll
    for (int m2=0;m2<4;m2++) af[m2] = *(const bf16x8*)(lA + (ra+m2*16)*32 + cb);
    #pragma unroll
    for (int n2=0;n2<4;n2++) bfr[n2] = *(const bf16x8*)(lB + (rb+n2*16)*32 + cb);
    #pragma unroll
    for (int m2=0;m2<4;m2++)
      #pragma unroll
      for (int n2=0;n2<4;n2++)
        acc[m2][n2] = __builtin_amdgcn_mfma_f32_16x16x32_bf16(af[m2], bfr[n2], acc[m2][n2], 0,0,0);
  }
  int rr = (lane>>4)<<2, cc = lane&15;
  #pragma unroll
  for (int m2=0;m2<4;m2++){
    #pragma unroll
    for (int n2=0;n2<4;n2++){
      int col = (bn<<7) + (wc<<6) + (n2<<4) + cc;
      float bs = bias[col];
      #pragma unroll
      for (int j=0;j<4;j++){
        int row = (bm<<7) + (wr<<6) + (m2<<4) + rr + j;
        float v = acc[m2][n2][j] + bs;
        if (EPI==0){
          float sv = v * (1.0f/(1.0f+expf(-v)));
          if (col < DI) bout0[(size_t)row*DI + col] = f2b(sv);
          else          bout1[(size_t)row*DI + col - DI] = f2b(sv);
        } else if (EPI==1){
          size_t oi=(size_t)row*Ndim+col;
          fout[oi] = addin[oi] + v;
        } else {
          size_t oi=(size_t)row*Ndim+col;
          bout0[oi] = f2b(0.5f*v*(1.0f+erff(v*0.70710678118f)));
        }
      }
    }
  }
}

template<int EPI>
__global__ __launch_bounds__(256) void k_gemm(
    const unsigned short* __restrict__ A, const unsigned short* __restrict__ BT,
    const float* __restrict__ bias, int Ndim, int K,
    const float* __restrict__ addin, float* __restrict__ fout,
    unsigned short* __restrict__ bout0, unsigned short* __restrict__ bout1)
{
  __shared__ __align__(16) unsigned short lAB[128*32*2];
  int ntn = Ndim>>7;
  int bm = blockIdx.x/ntn, bn = blockIdx.x - bm*ntn;
  gemm_body<EPI>(lAB, lAB+128*32, bm, bn, A, BT, bias, Ndim, K, addin, fout, bout0, bout1);
}

// ---------------- fused: Prim (blocks 0-15, dispatched first) + gemm<0> tiles ----------------
__global__ __launch_bounds__(256) void k_fused(
    const unsigned short* __restrict__ xn, const unsigned short* __restrict__ WinT,
    const float* __restrict__ b_in,
    unsigned short* __restrict__ xi_b, unsigned short* __restrict__ sz_b,
    const float* __restrict__ wgt, int* __restrict__ par_g,
    int* __restrict__ lvlorder, int* __restrict__ lvlstart, int* __restrict__ nlvl)
{
  __shared__ __align__(16) unsigned char smem[55296];
  if (blockIdx.x < BB){
    if (threadIdx.x >= 64) return;
    prim_body(smem, wgt, blockIdx.x, par_g, lvlorder, lvlstart, nlvl);
  } else {
    int bid = blockIdx.x - BB;
    int bm = bid>>3, bn = bid&7;
    gemm_body<0>((unsigned short*)smem, (unsigned short*)smem + 128*32, bm, bn,
                 xn, WinT, b_in, 1024, 256, nullptr, nullptr, xi_b, sz_b);
  }
}

// ---------------- LayerNorm -> bf16 ----------------
__global__ __launch_bounds__(256) void k_ln(const float* __restrict__ xin, const float* __restrict__ g,
    const float* __restrict__ bta, unsigned short* __restrict__ outb)
{
  int row = blockIdx.x*4 + (threadIdx.x>>6); int lane=threadIdx.x&63;
  float4 v = *(const float4*)(xin + (size_t)row*CC + lane*4);
  float s = v.x+v.y+v.z+v.w;
  #pragma unroll
  for (int o=32;o;o>>=1) s += __shfl_xor(s,o);
  float m = s*(1.0f/256.0f);
  float dx=v.x-m, dy=v.y-m, dz=v.z-m, dw=v.w-m;
  float ss=dx*dx+dy*dy+dz*dz+dw*dw;
  #pragma unroll
  for (int o=32;o;o>>=1) ss += __shfl_xor(ss,o);
  float rs = rsqrtf(ss*(1.0f/256.0f)+1e-5f);
  int cb=lane*4;
  unsigned o0 = (unsigned)f2b(dx*rs*g[cb+0]+bta[cb+0]) | ((unsigned)f2b(dy*rs*g[cb+1]+bta[cb+1])<<16);
  unsigned o1 = (unsigned)f2b(dz*rs*g[cb+2]+bta[cb+2]) | ((unsigned)f2b(dw*rs*g[cb+3]+bta[cb+3])<<16);
  *(uint2*)(outb + (size_t)row*CC + cb) = make_uint2(o0,o1);
}

// ---------------- dbc = xi @ W_xp  (18 cols) ----------------
__global__ __launch_bounds__(256) void k_dbc(const unsigned short* __restrict__ xi_b,
    const float* __restrict__ WxpT, float* __restrict__ dbc)
{
  int row = blockIdx.x*4 + (threadIdx.x>>6); int lane=threadIdx.x&63;
  int4 raw = *(const int4*)(xi_b + (size_t)row*DI + lane*8);
  float xf[8];
  xf[0]=b2f((unsigned short)((unsigned)raw.x&0xFFFFu)); xf[1]=b2f((unsigned short)((unsigned)raw.x>>16));
  xf[2]=b2f((unsigned short)((unsigned)raw.y&0xFFFFu)); xf[3]=b2f((unsigned short)((unsigned)raw.y>>16));
  xf[4]=b2f((unsigned short)((unsigned)raw.z&0xFFFFu)); xf[5]=b2f((unsigned short)((unsigned)raw.z>>16));
  xf[6]=b2f((unsigned short)((unsigned)raw.w&0xFFFFu)); xf[7]=b2f((unsigned short)((unsigned)raw.w>>16));
  for (int jc=0;jc<18;jc++){
    const float* wr_ = WxpT + (size_t)jc*DI + lane*8;
    float s=0.f;
    #pragma unroll
    for (int t=0;t<8;t++) s += xf[t]*wr_[t];
    #pragma unroll
    for (int o=32;o;o>>=1) s += __shfl_xor(s,o);
    if (lane==0) dbc[(size_t)row*18+jc]=s;
  }
}

// ---------------- dt/softplus -> decay (bf16), Bx (bf16) ----------------
__global__ __launch_bounds__(512) void k_dbx(const float* __restrict__ dbc, const unsigned short* __restrict__ xi_b,
  const float* __restrict__ W_dt, const float* __restrict__ b_dt, const float* __restrict__ A_log,
  unsigned short* __restrict__ decay, unsigned short* __restrict__ Bx)
{
  int row=blockIdx.x, c=threadIdx.x;
  __shared__ float sd[18];
  if (c<18) sd[c]=dbc[(size_t)row*18+c];
  __syncthreads();
  float a=b_dt[c];
  #pragma unroll
  for (int r2=0;r2<16;r2++) a += sd[r2]*W_dt[r2*DI+c];
  float dt = (a>20.f)? a : log1pf(expf(a));
  size_t o=(size_t)row*DI+c;
  decay[o]=f2b(expf(dt * -expf(A_log[c])));
  Bx[o]=f2b(dt*sd[16]*b2f(xi_b[o]));
}

// ---------------- level-parallel tree scan, 4 channels/block in LDS ----------------
#define SCH 4
__global__ __launch_bounds__(256) void k_scan(const unsigned short* __restrict__ decay,
    unsigned short* __restrict__ bxh,
    const int* __restrict__ par_g, const int* __restrict__ lvlorder, const int* __restrict__ lvlstart,
    const int* __restrict__ nlvl)
{
  __shared__ unsigned short sdec[NN*SCH];
  __shared__ unsigned short sbx[NN*SCH];
  __shared__ int sord[NN];
  __shared__ unsigned short spar[NN];
  int b = blockIdx.x>>7, t = blockIdx.x&127;
  int c0 = t*SCH;
  int tid = threadIdx.x;
  const size_t gbase = (size_t)b*NN*DI;
  for (int i=tid; i<NN*2; i+=256){
    int node=i>>1, p=i&1;
    size_t go = gbase + (size_t)node*DI + c0 + p*2;
    *(unsigned*)&sdec[node*SCH+p*2] = *(const unsigned*)&decay[go];
    *(unsigned*)&sbx [node*SCH+p*2] = *(const unsigned*)&bxh[go];
  }
  for (int i=tid;i<NN;i+=256){ sord[i]=lvlorder[b*NN+i]; spar[i]=(unsigned short)par_g[b*NN+i]; }
  int nlv = nlvl[b];
  __syncthreads();
  for (int lvl=1; lvl<nlv; lvl++){
    int s=lvlstart[b*(NN+2)+lvl], e=lvlstart[b*(NN+2)+lvl+1];
    int tot=(e-s)*SCH;
    for (int idx=tid; idx<tot; idx+=256){
      int node = sord[s + (idx>>2)];
      int cc = idx&3;
      int pv = spar[node];
      float hv = b2f(sdec[node*SCH+cc])*b2f(sbx[pv*SCH+cc]) + b2f(sbx[node*SCH+cc]);
      sbx[node*SCH+cc] = f2b(hv);
    }
    __syncthreads();
  }
  for (int i=tid; i<NN*2; i+=256){
    int node=i>>1, p=i&1;
    size_t go = gbase + (size_t)node*DI + c0 + p*2;
    *(unsigned*)&bxh[go] = *(const unsigned*)&sbx[node*SCH+p*2];
  }
}

// ---------------- u = (Cv*h + Dp*xi) * silu(z) -> bf16 (in place over sz) ----------------
__global__ __launch_bounds__(256) void k_u(const unsigned short* __restrict__ h, const unsigned short* __restrict__ xi_b,
    const unsigned short* __restrict__ sz_b, const float* __restrict__ dbc, const float* __restrict__ Dp,
    unsigned short* __restrict__ u_b)
{
  int g8 = blockIdx.x*256 + threadIdx.x;
  int row = g8>>6; int cb=(g8&63)*8;
  size_t o = (size_t)row*DI + cb;
  float Cv = dbc[(size_t)row*18+17];
  int4 xi = *(const int4*)(xi_b+o);
  int4 sz = *(const int4*)(sz_b+o);
  int4 hh = *(const int4*)(h+o);
  int   xw[4] = {xi.x,xi.y,xi.z,xi.w};
  int   sw[4] = {sz.x,sz.y,sz.z,sz.w};
  int   hw[4] = {hh.x,hh.y,hh.z,hh.w};
  unsigned ov[4];
  #pragma unroll
  for (int q=0;q<4;q++){
    float xlo=b2f((unsigned short)((unsigned)xw[q]&0xFFFFu)), xhi=b2f((unsigned short)((unsigned)xw[q]>>16));
    float slo=b2f((unsigned short)((unsigned)sw[q]&0xFFFFu)), shi=b2f((unsigned short)((unsigned)sw[q]>>16));
    float hlo=b2f((unsigned short)((unsigned)hw[q]&0xFFFFu)), hhi=b2f((unsigned short)((unsigned)hw[q]>>16));
    float ylo=(Cv*hlo + Dp[cb+2*q+0]*xlo)*slo;
    float yhi=(Cv*hhi + Dp[cb+2*q+1]*xhi)*shi;
    ov[q] = (unsigned)f2b(ylo) | ((unsigned)f2b(yhi)<<16);
  }
  int4 outv; outv.x=(int)ov[0]; outv.y=(int)ov[1]; outv.z=(int)ov[2]; outv.w=(int)ov[3];
  *(int4*)(u_b+o) = outv;
}

// ---------------- launch ----------------
extern "C" void kernel_launch(void* const* d_in, const int* in_sizes, int n_in,
                              void* d_out, int out_size, void* d_ws, size_t ws_size,
                              hipStream_t stream) {
  (void)in_sizes; (void)n_in; (void)out_size; (void)ws_size;
  const float* x      = (const float*)d_in[0];
  const float* n1w    = (const float*)d_in[1];
  const float* n1b    = (const float*)d_in[2];
  const float* n2w    = (const float*)d_in[3];
  const float* n2b    = (const float*)d_in[4];
  const float* W_in   = (const float*)d_in[5];
  const float* b_in   = (const float*)d_in[6];
  const float* W_xp   = (const float*)d_in[7];
  const float* W_dt   = (const float*)d_in[8];
  const float* b_dt   = (const float*)d_in[9];
  const float* A_log  = (const float*)d_in[10];
  const float* Dp     = (const float*)d_in[11];
  const float* W_out  = (const float*)d_in[12];
  const float* b_out  = (const float*)d_in[13];
  const float* fc1_w  = (const float*)d_in[14];
  const float* fc1_b  = (const float*)d_in[15];
  const float* fc2_w  = (const float*)d_in[16];
  const float* fc2_b  = (const float*)d_in[17];

  char* base=(char*)d_ws; size_t off=0;
  auto alc=[&](size_t nb)->char*{ char* p=base+off; off=(off+nb+255)&~(size_t)255; return p; };
  float* wgt            = (float*)alc((size_t)MM*4*4);
  float* innorm         = (float*)alc((size_t)MM*4);
  int* par_g            = (int*)alc((size_t)MM*4);
  int* lvlorder         = (int*)alc((size_t)MM*4);
  int* lvlstart         = (int*)alc((size_t)BB*(NN+2)*4);
  int* nlvl             = (int*)alc((size_t)BB*4);
  unsigned short* xi_b  = (unsigned short*)alc((size_t)MM*DI*2);
  unsigned short* sz_b  = (unsigned short*)alc((size_t)MM*DI*2);   // contiguous after xi_b
  float* dbc            = (float*)alc((size_t)MM*18*4);
  unsigned short* dec_b = (unsigned short*)alc((size_t)MM*DI*2);
  unsigned short* bxh_b = (unsigned short*)alc((size_t)MM*DI*2);
  unsigned short* WinT  = (unsigned short*)alc((size_t)CC*1024*2);
  unsigned short* WoutT = (unsigned short*)alc((size_t)DI*CC*2);
  unsigned short* fc1T  = (unsigned short*)alc((size_t)CC*1024*2);
  unsigned short* fc2T  = (unsigned short*)alc((size_t)1024*CC*2);
  float* WxpT           = (float*)alc((size_t)DI*18*4);
  // lifetime-based aliases:
  unsigned short* xn    = (unsigned short*)dec_b;   // [MM][256] bf16; dead before k_dbx writes dec_b
  unsigned short* u_b   = sz_b;                     // in-place over sz
  float* x2             = (float*)dec_b;            // [MM][256] f32; dec dead after scan
  unsigned short* x2n   = bxh_b;                    // [MM][256] bf16; h dead after k_u
  unsigned short* g1_b  = xi_b;                     // [MM][1024] bf16; spans xi_b+sz_b

  k_wconv<<<dim3((256*1024+255)/256),dim3(256),0,stream>>>(W_in, WinT, 256,1024);
  k_wconv<<<dim3((512*256 +255)/256),dim3(256),0,stream>>>(W_out, WoutT, 512,256);
  k_wconv<<<dim3((256*1024+255)/256),dim3(256),0,stream>>>(fc1_w, fc1T, 256,1024);
  k_wconv<<<dim3((1024*256+255)/256),dim3(256),0,stream>>>(fc2_w, fc2T, 1024,256);
  k_t32  <<<dim3((512*18  +255)/256),dim3(256),0,stream>>>(W_xp, WxpT, 512,18);

  k_norm<<<dim3(MM/4),dim3(256),0,stream>>>(x, innorm);
  k_edge<<<dim3(MM/4),dim3(256),0,stream>>>(x, innorm, wgt);
  k_ln<<<dim3(MM/4),dim3(256),0,stream>>>(x, n1w, n1b, xn);

  // Prim (blocks 0-15, starts immediately) + gemm<0> (2304 tile blocks) in one launch
  k_fused<<<dim3(BB + 288*8),dim3(256),0,stream>>>(xn, WinT, b_in, xi_b, sz_b,
                                                   wgt, par_g, lvlorder, lvlstart, nlvl);

  k_dbc<<<dim3(MM/4),dim3(256),0,stream>>>(xi_b, WxpT, dbc);
  k_dbx<<<dim3(MM),dim3(512),0,stream>>>(dbc, xi_b, W_dt, b_dt, A_log, dec_b, bxh_b);
  k_scan<<<dim3(BB*128),dim3(256),0,stream>>>(dec_b, bxh_b, par_g, lvlorder, lvlstart, nlvl);
  k_u<<<dim3(MM*64/256),dim3(256),0,stream>>>(bxh_b, xi_b, sz_b, dbc, Dp, u_b);
  k_gemm<1><<<dim3(288*2),dim3(256),0,stream>>>(u_b, WoutT, b_out, 256, 512, x, x2, nullptr, nullptr);

  k_ln<<<dim3(MM/4),dim3(256),0,stream>>>(x2, n2w, n2b, x2n);
  k_gemm<2><<<dim3(288*8),dim3(256),0,stream>>>(x2n, fc1T, fc1_b, 1024, 256, nullptr, nullptr, g1_b, nullptr);
  k_gemm<1><<<dim3(288*2),dim3(256),0,stream>>>(g1_b, fc2T, fc2_b, 256, 1024, x2, (float*)d_out, nullptr, nullptr);
}

// Round 5
// 933.671 us; speedup vs baseline: 4.0305x; 2.3647x over previous
//
#include <hip/hip_runtime.h>
#include <math.h>

#define NN 2304
#define BB 16
#define CC 256
#define DI 512
#define MM (BB*NN)   // 36864

typedef __attribute__((ext_vector_type(8))) short bf16x8;
typedef __attribute__((ext_vector_type(4))) float f32x4;

__device__ inline unsigned short f2b(float f){
  unsigned u = __float_as_uint(f);
  u = u + 0x7FFFu + ((u>>16)&1u);
  return (unsigned short)(u>>16);
}
__device__ inline float b2f(unsigned short s){ return __uint_as_float(((unsigned)s)<<16); }

// ---------------- weight convert / transpose ----------------
__global__ __launch_bounds__(256) void k_wconv(const float* __restrict__ in, unsigned short* __restrict__ out, int R, int Ccols){
  int idx = blockIdx.x*256 + threadIdx.x;
  if (idx >= R*Ccols) return;
  int r = idx / Ccols, c = idx - r*Ccols;
  out[(size_t)c*R + r] = f2b(in[idx]);
}
__global__ __launch_bounds__(256) void k_t32(const float* __restrict__ in, float* __restrict__ out, int R, int Ccols){
  int idx = blockIdx.x*256 + threadIdx.x;
  if (idx >= R*Ccols) return;
  int r = idx / Ccols, c = idx - r*Ccols;
  out[(size_t)c*R + r] = in[idx];
}

// ---------------- feature norms ----------------
__global__ __launch_bounds__(256) void k_norm(const float* __restrict__ x, float* __restrict__ innorm){
  int row = blockIdx.x*4 + (threadIdx.x>>6); int lane = threadIdx.x&63;
  float4 v = *(const float4*)(x + (size_t)row*CC + lane*4);
  float s = v.x*v.x + v.y*v.y + v.z*v.z + v.w*v.w;
  #pragma unroll
  for (int o=32;o;o>>=1) s += __shfl_xor(s,o);
  if (lane==0) innorm[row] = 1.0f/(sqrtf(s)+1e-8f);
}

// ---------------- edge weights exp(1-cos) ----------------
__global__ __launch_bounds__(256) void k_edge(const float* __restrict__ x, const float* __restrict__ innorm, float* __restrict__ wgt){
  int g = blockIdx.x*4 + (threadIdx.x>>6); int lane = threadIdx.x&63;
  int b = g/NN, n = g - b*NN;
  int r = n/48, c = n - (n/48)*48;
  const float* xb = x + ((size_t)b*NN)*CC;
  float4 vu = *(const float4*)(xb + (size_t)n*CC + lane*4);
  int nb0=(r>0)?n-48:-1, nb1=(r<47)?n+48:-1, nb2=(c>0)?n-1:-1, nb3=(c<47)?n+1:-1;
  float d0=0,d1=0,d2=0,d3=0;
  if (nb0>=0){ float4 t=*(const float4*)(xb+(size_t)nb0*CC+lane*4); d0=vu.x*t.x+vu.y*t.y+vu.z*t.z+vu.w*t.w; }
  if (nb1>=0){ float4 t=*(const float4*)(xb+(size_t)nb1*CC+lane*4); d1=vu.x*t.x+vu.y*t.y+vu.z*t.z+vu.w*t.w; }
  if (nb2>=0){ float4 t=*(const float4*)(xb+(size_t)nb2*CC+lane*4); d2=vu.x*t.x+vu.y*t.y+vu.z*t.z+vu.w*t.w; }
  if (nb3>=0){ float4 t=*(const float4*)(xb+(size_t)nb3*CC+lane*4); d3=vu.x*t.x+vu.y*t.y+vu.z*t.z+vu.w*t.w; }
  #pragma unroll
  for (int o=32;o;o>>=1){ d0+=__shfl_xor(d0,o); d1+=__shfl_xor(d1,o); d2+=__shfl_xor(d2,o); d3+=__shfl_xor(d3,o); }
  if (lane==0){
    float inu = innorm[g];
    float inf_ = __uint_as_float(0x7F800000u);
    float4 w;
    w.x = (nb0>=0)? expf(1.0f - d0*(inu*innorm[g-n+nb0])) : inf_;
    w.y = (nb1>=0)? expf(1.0f - d1*(inu*innorm[g-n+nb1])) : inf_;
    w.z = (nb2>=0)? expf(1.0f - d2*(inu*innorm[g-n+nb2])) : inf_;
    w.w = (nb3>=0)? expf(1.0f - d3*(inu*innorm[g-n+nb3])) : inf_;
    *(float4*)(wgt + (size_t)g*4) = w;
  }
}

// ---------------- MST via Boruvka + BFS root/level (256 threads, all-parallel) ----------------
// Distinct weights => unique MST == reference Prim tree. BFS from node 0 yields par,
// level order (frontiers), level starts. Ties: negligible output effect; no-hang by design.
#define INFB 0x7F800000u
__device__ void mst_body(unsigned char* smem, const float* __restrict__ wgt, int b,
    int* __restrict__ par_g, int* __restrict__ lvlorder, int* __restrict__ lvlstart, int* __restrict__ nlvl)
{
  unsigned* comp   = (unsigned*)smem;               //  9216
  unsigned* bestw  = (unsigned*)(smem + 9216);      //  9216
  unsigned* bestid = (unsigned*)(smem + 18432);     //  9216
  unsigned* tmask  = (unsigned*)(smem + 27648);     //  9216
  unsigned* parpd  = (unsigned*)(smem + 36864);     //  9216
  unsigned short* fr0 = (unsigned short*)(smem + 46080); // 4608
  unsigned short* fr1 = (unsigned short*)(smem + 50688); // 4608
  int* ctr = (int*)(smem + 55296);                  // 16
  const int tid = threadIdx.x;
  const float* wb = wgt + (size_t)b*NN*4;

  #pragma unroll
  for (int k=0;k<9;k++){ int v=tid+k*256; comp[v]=v; tmask[v]=0u; }
  __syncthreads();

  for (int round=0; round<14; round++){
    #pragma unroll
    for (int k=0;k<9;k++){ int v=tid+k*256; bestw[v]=INFB; bestid[v]=0xFFFFFFFFu; }
    __syncthreads();
    // find per-node min outgoing edge (to a different component)
    unsigned candw[9], candi[9];
    #pragma unroll
    for (int k=0;k<9;k++){
      int v=tid+k*256;
      unsigned cv=comp[v];
      int r=v/48, c=v-(v/48)*48;
      float4 w4 = *(const float4*)(wb + (size_t)v*4);
      unsigned cw=INFB, ci=0xFFFFFFFFu;
      if (r>0  && comp[v-48]!=cv){ unsigned wv=__float_as_uint(w4.x); if (wv<cw){cw=wv;ci=(unsigned)(v*4+0);} }
      if (r<47 && comp[v+48]!=cv){ unsigned wv=__float_as_uint(w4.y); if (wv<cw){cw=wv;ci=(unsigned)(v*4+1);} }
      if (c>0  && comp[v-1] !=cv){ unsigned wv=__float_as_uint(w4.z); if (wv<cw){cw=wv;ci=(unsigned)(v*4+2);} }
      if (c<47 && comp[v+1] !=cv){ unsigned wv=__float_as_uint(w4.w); if (wv<cw){cw=wv;ci=(unsigned)(v*4+3);} }
      candw[k]=cw; candi[k]=ci;
      if (cw!=INFB) atomicMin(&bestw[cv], cw);
    }
    __syncthreads();
    // deterministic argmin id (min id among weight-equal)
    #pragma unroll
    for (int k=0;k<9;k++){
      if (candw[k]!=INFB){
        int v=tid+k*256; unsigned cv=comp[v];
        if (bestw[cv]==candw[k]) atomicMin(&bestid[cv], candi[k]);
      }
    }
    __syncthreads();
    // hook decision (read-only phase)
    unsigned hookS[9];
    #pragma unroll
    for (int k=0;k<9;k++){
      int v=tid+k*256; hookS[k]=0xFFFFFFFFu;
      if (comp[v]!=(unsigned)v) continue;
      unsigned id=bestid[v];
      if (id==0xFFFFFFFFu) continue;
      int u=(int)(id>>2), d=(int)(id&3);
      int o = u + ((d==0)?-48:(d==1)?48:(d==2)?-1:1);
      unsigned s = comp[o];
      unsigned sid = bestid[s];
      bool mutual=false;
      if (sid!=0xFFFFFFFFu){
        int su=(int)(sid>>2), sd=(int)(sid&3);
        int so = su + ((sd==0)?-48:(sd==1)?48:(sd==2)?-1:1);
        mutual = (comp[so]==(unsigned)v);
      }
      if (!mutual || (unsigned)v>s) hookS[k]=s;
    }
    __syncthreads();
    // apply hooks + record tree edges
    #pragma unroll
    for (int k=0;k<9;k++){
      if (hookS[k]==0xFFFFFFFFu) continue;
      int v=tid+k*256;
      unsigned id=bestid[v];
      int u=(int)(id>>2), d=(int)(id&3);
      int o = u + ((d==0)?-48:(d==1)?48:(d==2)?-1:1);
      comp[v]=hookS[k];
      atomicOr(&tmask[u], 1u<<d);
      atomicOr(&tmask[o], 1u<<(d^1));
    }
    __syncthreads();
    // pointer jumping to flat
    for (int it=0; it<16; it++){
      if (tid==0) ctr[1]=0;
      __syncthreads();
      int ch=0;
      #pragma unroll
      for (int k=0;k<9;k++){
        int v=tid+k*256;
        unsigned c1=comp[v], c2=comp[c1];
        if (c1!=c2){ comp[v]=c2; ch=1; }
      }
      if (ch) atomicAdd(&ctr[1],1);
      __syncthreads();
      if (ctr[1]==0) break;
    }
    // component count, early exit
    if (tid==0) ctr[2]=0;
    __syncthreads();
    int rc=0;
    #pragma unroll
    for (int k=0;k<9;k++){ int v=tid+k*256; if (comp[v]==(unsigned)v) rc++; }
    if (rc) atomicAdd(&ctr[2], rc);
    __syncthreads();
    if (ctr[2]<=1) break;
  }
  // ---- BFS from node 0 over tmask: par, levels, order ----
  #pragma unroll
  for (int k=0;k<9;k++){ int v=tid+k*256; parpd[v]=0xFFFFFFFFu; }
  __syncthreads();
  if (tid==0){
    parpd[0]=0u; fr0[0]=0;
    lvlstart[b*(NN+2)+0]=0;
    lvlorder[b*NN+0]=0;
  }
  __syncthreads();
  unsigned short* frA=fr0; unsigned short* frB=fr1;
  int lvl=0, off=0, cnt=1;
  while (true){
    if (tid==0) ctr[0]=0;
    __syncthreads();
    for (int i=tid;i<cnt;i+=256){
      int v=(int)frA[i];
      unsigned m=tmask[v];
      int pv=(int)(parpd[v]&0xFFFFu);
      #pragma unroll
      for (int d=0;d<4;d++){
        if ((m>>d)&1u){
          int nb = v + ((d==0)?-48:(d==1)?48:(d==2)?-1:1);
          if (nb!=pv){
            unsigned nv=((unsigned)(lvl+1)<<16)|(unsigned)v;
            if (atomicCAS(&parpd[nb], 0xFFFFFFFFu, nv)==0xFFFFFFFFu){
              int pos=atomicAdd(&ctr[0],1);
              frB[pos]=(unsigned short)nb;
            }
          }
        }
      }
    }
    __syncthreads();
    int ncnt=ctr[0];
    if (ncnt==0) break;
    if (tid==0) lvlstart[b*(NN+2)+(lvl+1)] = off+cnt;
    for (int i=tid;i<ncnt;i+=256) lvlorder[b*NN + off+cnt + i] = (int)frB[i];
    off+=cnt; cnt=ncnt; lvl++;
    unsigned short* t=frA; frA=frB; frB=t;
    __syncthreads();
  }
  if (tid==0){ nlvl[b]=lvl+1; lvlstart[b*(NN+2)+(lvl+1)]=off+cnt; }
  #pragma unroll
  for (int k=0;k<9;k++){ int v=tid+k*256; par_g[b*NN+v]=(int)(parpd[v]&0xFFFFu); }
}

// ---------------- bf16 MFMA GEMM body, 128x128 tile, fused epilogues ----------------
template<int EPI>
__device__ void gemm_body(unsigned short* lA, unsigned short* lB, int bm, int bn,
    const unsigned short* __restrict__ A, const unsigned short* __restrict__ BT,
    const float* __restrict__ bias, int Ndim, int K,
    const float* __restrict__ addin, float* __restrict__ fout,
    unsigned short* __restrict__ bout0, unsigned short* __restrict__ bout1)
{
  int tid=threadIdx.x, wid=tid>>6, lane=tid&63;
  const unsigned short* Ab = A + (size_t)bm*128*K;
  const unsigned short* Bb = BT + (size_t)bn*128*K;
  int wr=wid>>1, wc=wid&1;
  f32x4 acc[4][4];
  #pragma unroll
  for (int m2=0;m2<4;m2++)
    #pragma unroll
    for (int n2=0;n2<4;n2++)
      #pragma unroll
      for (int j=0;j<4;j++) acc[m2][n2][j]=0.f;
  int r0 = tid>>2, c0 = (tid&3)*8;
  for (int k0=0;k0<K;k0+=32){
    int4 va0 = *(const int4*)(Ab + (size_t)r0*K + k0 + c0);
    int4 va1 = *(const int4*)(Ab + (size_t)(r0+64)*K + k0 + c0);
    int4 vb0 = *(const int4*)(Bb + (size_t)r0*K + k0 + c0);
    int4 vb1 = *(const int4*)(Bb + (size_t)(r0+64)*K + k0 + c0);
    __syncthreads();
    *(int4*)(lA + r0*32 + c0) = va0;
    *(int4*)(lA + (r0+64)*32 + c0) = va1;
    *(int4*)(lB + r0*32 + c0) = vb0;
    *(int4*)(lB + (r0+64)*32 + c0) = vb1;
    __syncthreads();
    int ra = (wr<<6) + (lane&15);
    int rb = (wc<<6) + (lane&15);
    int cb = (lane>>4)<<3;
    bf16x8 af[4], bfr[4];
    #pragma unroll
    for (int m2=0;m2<4;m2++) af[m2] = *(const bf16x8*)(lA + (ra+m2*16)*32 + cb);
    #pragma unroll
    for (int n2=0;n2<4;n2++) bfr[n2] = *(const bf16x8*)(lB + (rb+n2*16)*32 + cb);
    #pragma unroll
    for (int m2=0;m2<4;m2++)
      #pragma unroll
      for (int n2=0;n2<4;n2++)
        acc[m2][n2] = __builtin_amdgcn_mfma_f32_16x16x32_bf16(af[m2], bfr[n2], acc[m2][n2], 0,0,0);
  }
  int rr = (lane>>4)<<2, cc = lane&15;
  #pragma unroll
  for (int m2=0;m2<4;m2++){
    #pragma unroll
    for (int n2=0;n2<4;n2++){
      int col = (bn<<7) + (wc<<6) + (n2<<4) + cc;
      float bs = bias[col];
      #pragma unroll
      for (int j=0;j<4;j++){
        int row = (bm<<7) + (wr<<6) + (m2<<4) + rr + j;
        float v = acc[m2][n2][j] + bs;
        if (EPI==0){
          float sv = v * (1.0f/(1.0f+expf(-v)));
          if (col < DI) bout0[(size_t)row*DI + col] = f2b(sv);
          else          bout1[(size_t)row*DI + col - DI] = f2b(sv);
        } else if (EPI==1){
          size_t oi=(size_t)row*Ndim+col;
          fout[oi] = addin[oi] + v;
        } else {
          size_t oi=(size_t)row*Ndim+col;
          bout0[oi] = f2b(0.5f*v*(1.0f+erff(v*0.70710678118f)));
        }
      }
    }
  }
}

template<int EPI>
__global__ __launch_bounds__(256) void k_gemm(
    const unsigned short* __restrict__ A, const unsigned short* __restrict__ BT,
    const float* __restrict__ bias, int Ndim, int K,
    const float* __restrict__ addin, float* __restrict__ fout,
    unsigned short* __restrict__ bout0, unsigned short* __restrict__ bout1)
{
  __shared__ __align__(16) unsigned short lAB[128*32*2];
  int ntn = Ndim>>7;
  int bm = blockIdx.x/ntn, bn = blockIdx.x - bm*ntn;
  gemm_body<EPI>(lAB, lAB+128*32, bm, bn, A, BT, bias, Ndim, K, addin, fout, bout0, bout1);
}

// ---------------- fused: MST (blocks 0-15) + gemm<0> tiles ----------------
__global__ __launch_bounds__(256) void k_fused(
    const unsigned short* __restrict__ xn, const unsigned short* __restrict__ WinT,
    const float* __restrict__ b_in,
    unsigned short* __restrict__ xi_b, unsigned short* __restrict__ sz_b,
    const float* __restrict__ wgt, int* __restrict__ par_g,
    int* __restrict__ lvlorder, int* __restrict__ lvlstart, int* __restrict__ nlvl)
{
  __shared__ __align__(16) unsigned char smem[55424];
  if (blockIdx.x < BB){
    mst_body(smem, wgt, blockIdx.x, par_g, lvlorder, lvlstart, nlvl);
  } else {
    int bid = blockIdx.x - BB;
    int bm = bid>>3, bn = bid&7;
    gemm_body<0>((unsigned short*)smem, (unsigned short*)smem + 128*32, bm, bn,
                 xn, WinT, b_in, 1024, 256, nullptr, nullptr, xi_b, sz_b);
  }
}

// ---------------- LayerNorm -> bf16 ----------------
__global__ __launch_bounds__(256) void k_ln(const float* __restrict__ xin, const float* __restrict__ g,
    const float* __restrict__ bta, unsigned short* __restrict__ outb)
{
  int row = blockIdx.x*4 + (threadIdx.x>>6); int lane=threadIdx.x&63;
  float4 v = *(const float4*)(xin + (size_t)row*CC + lane*4);
  float s = v.x+v.y+v.z+v.w;
  #pragma unroll
  for (int o=32;o;o>>=1) s += __shfl_xor(s,o);
  float m = s*(1.0f/256.0f);
  float dx=v.x-m, dy=v.y-m, dz=v.z-m, dw=v.w-m;
  float ss=dx*dx+dy*dy+dz*dz+dw*dw;
  #pragma unroll
  for (int o=32;o;o>>=1) ss += __shfl_xor(ss,o);
  float rs = rsqrtf(ss*(1.0f/256.0f)+1e-5f);
  int cb=lane*4;
  unsigned o0 = (unsigned)f2b(dx*rs*g[cb+0]+bta[cb+0]) | ((unsigned)f2b(dy*rs*g[cb+1]+bta[cb+1])<<16);
  unsigned o1 = (unsigned)f2b(dz*rs*g[cb+2]+bta[cb+2]) | ((unsigned)f2b(dw*rs*g[cb+3]+bta[cb+3])<<16);
  *(uint2*)(outb + (size_t)row*CC + cb) = make_uint2(o0,o1);
}

// ---------------- dbc = xi @ W_xp  (18 cols) ----------------
__global__ __launch_bounds__(256) void k_dbc(const unsigned short* __restrict__ xi_b,
    const float* __restrict__ WxpT, float* __restrict__ dbc)
{
  int row = blockIdx.x*4 + (threadIdx.x>>6); int lane=threadIdx.x&63;
  int4 raw = *(const int4*)(xi_b + (size_t)row*DI + lane*8);
  float xf[8];
  xf[0]=b2f((unsigned short)((unsigned)raw.x&0xFFFFu)); xf[1]=b2f((unsigned short)((unsigned)raw.x>>16));
  xf[2]=b2f((unsigned short)((unsigned)raw.y&0xFFFFu)); xf[3]=b2f((unsigned short)((unsigned)raw.y>>16));
  xf[4]=b2f((unsigned short)((unsigned)raw.z&0xFFFFu)); xf[5]=b2f((unsigned short)((unsigned)raw.z>>16));
  xf[6]=b2f((unsigned short)((unsigned)raw.w&0xFFFFu)); xf[7]=b2f((unsigned short)((unsigned)raw.w>>16));
  for (int jc=0;jc<18;jc++){
    const float* wr_ = WxpT + (size_t)jc*DI + lane*8;
    float s=0.f;
    #pragma unroll
    for (int t=0;t<8;t++) s += xf[t]*wr_[t];
    #pragma unroll
    for (int o=32;o;o>>=1) s += __shfl_xor(s,o);
    if (lane==0) dbc[(size_t)row*18+jc]=s;
  }
}

// ---------------- dt/softplus -> decay (bf16), Bx (bf16) ----------------
__global__ __launch_bounds__(512) void k_dbx(const float* __restrict__ dbc, const unsigned short* __restrict__ xi_b,
  const float* __restrict__ W_dt, const float* __restrict__ b_dt, const float* __restrict__ A_log,
  unsigned short* __restrict__ decay, unsigned short* __restrict__ Bx)
{
  int row=blockIdx.x, c=threadIdx.x;
  __shared__ float sd[18];
  if (c<18) sd[c]=dbc[(size_t)row*18+c];
  __syncthreads();
  float a=b_dt[c];
  #pragma unroll
  for (int r2=0;r2<16;r2++) a += sd[r2]*W_dt[r2*DI+c];
  float dt = (a>20.f)? a : log1pf(expf(a));
  size_t o=(size_t)row*DI+c;
  decay[o]=f2b(expf(dt * -expf(A_log[c])));
  Bx[o]=f2b(dt*sd[16]*b2f(xi_b[o]));
}

// ---------------- level-parallel tree scan, 4 channels/block in LDS ----------------
#define SCH 4
__global__ __launch_bounds__(256) void k_scan(const unsigned short* __restrict__ decay,
    unsigned short* __restrict__ bxh,
    const int* __restrict__ par_g, const int* __restrict__ lvlorder, const int* __restrict__ lvlstart,
    const int* __restrict__ nlvl)
{
  __shared__ unsigned short sdec[NN*SCH];
  __shared__ unsigned short sbx[NN*SCH];
  __shared__ int sord[NN];
  __shared__ unsigned short spar[NN];
  int b = blockIdx.x>>7, t = blockIdx.x&127;
  int c0 = t*SCH;
  int tid = threadIdx.x;
  const size_t gbase = (size_t)b*NN*DI;
  for (int i=tid; i<NN*2; i+=256){
    int node=i>>1, p=i&1;
    size_t go = gbase + (size_t)node*DI + c0 + p*2;
    *(unsigned*)&sdec[node*SCH+p*2] = *(const unsigned*)&decay[go];
    *(unsigned*)&sbx [node*SCH+p*2] = *(const unsigned*)&bxh[go];
  }
  for (int i=tid;i<NN;i+=256){ sord[i]=lvlorder[b*NN+i]; spar[i]=(unsigned short)par_g[b*NN+i]; }
  int nlv = nlvl[b];
  __syncthreads();
  for (int lvl=1; lvl<nlv; lvl++){
    int s=lvlstart[b*(NN+2)+lvl], e=lvlstart[b*(NN+2)+lvl+1];
    int tot=(e-s)*SCH;
    for (int idx=tid; idx<tot; idx+=256){
      int node = sord[s + (idx>>2)];
      int cc = idx&3;
      int pv = spar[node];
      float hv = b2f(sdec[node*SCH+cc])*b2f(sbx[pv*SCH+cc]) + b2f(sbx[node*SCH+cc]);
      sbx[node*SCH+cc] = f2b(hv);
    }
    __syncthreads();
  }
  for (int i=tid; i<NN*2; i+=256){
    int node=i>>1, p=i&1;
    size_t go = gbase + (size_t)node*DI + c0 + p*2;
    *(unsigned*)&bxh[go] = *(const unsigned*)&sbx[node*SCH+p*2];
  }
}

// ---------------- u = (Cv*h + Dp*xi) * silu(z) -> bf16 (in place over sz) ----------------
__global__ __launch_bounds__(256) void k_u(const unsigned short* __restrict__ h, const unsigned short* __restrict__ xi_b,
    const unsigned short* __restrict__ sz_b, const float* __restrict__ dbc, const float* __restrict__ Dp,
    unsigned short* __restrict__ u_b)
{
  int g8 = blockIdx.x*256 + threadIdx.x;
  int row = g8>>6; int cb=(g8&63)*8;
  size_t o = (size_t)row*DI + cb;
  float Cv = dbc[(size_t)row*18+17];
  int4 xi = *(const int4*)(xi_b+o);
  int4 sz = *(const int4*)(sz_b+o);
  int4 hh = *(const int4*)(h+o);
  int   xw[4] = {xi.x,xi.y,xi.z,xi.w};
  int   sw[4] = {sz.x,sz.y,sz.z,sz.w};
  int   hw[4] = {hh.x,hh.y,hh.z,hh.w};
  unsigned ov[4];
  #pragma unroll
  for (int q=0;q<4;q++){
    float xlo=b2f((unsigned short)((unsigned)xw[q]&0xFFFFu)), xhi=b2f((unsigned short)((unsigned)xw[q]>>16));
    float slo=b2f((unsigned short)((unsigned)sw[q]&0xFFFFu)), shi=b2f((unsigned short)((unsigned)sw[q]>>16));
    float hlo=b2f((unsigned short)((unsigned)hw[q]&0xFFFFu)), hhi=b2f((unsigned short)((unsigned)hw[q]>>16));
    float ylo=(Cv*hlo + Dp[cb+2*q+0]*xlo)*slo;
    float yhi=(Cv*hhi + Dp[cb+2*q+1]*xhi)*shi;
    ov[q] = (unsigned)f2b(ylo) | ((unsigned)f2b(yhi)<<16);
  }
  int4 outv; outv.x=(int)ov[0]; outv.y=(int)ov[1]; outv.z=(int)ov[2]; outv.w=(int)ov[3];
  *(int4*)(u_b+o) = outv;
}

// ---------------- launch ----------------
extern "C" void kernel_launch(void* const* d_in, const int* in_sizes, int n_in,
                              void* d_out, int out_size, void* d_ws, size_t ws_size,
                              hipStream_t stream) {
  (void)in_sizes; (void)n_in; (void)out_size; (void)ws_size;
  const float* x      = (const float*)d_in[0];
  const float* n1w    = (const float*)d_in[1];
  const float* n1b    = (const float*)d_in[2];
  const float* n2w    = (const float*)d_in[3];
  const float* n2b    = (const float*)d_in[4];
  const float* W_in   = (const float*)d_in[5];
  const float* b_in   = (const float*)d_in[6];
  const float* W_xp   = (const float*)d_in[7];
  const float* W_dt   = (const float*)d_in[8];
  const float* b_dt   = (const float*)d_in[9];
  const float* A_log  = (const float*)d_in[10];
  const float* Dp     = (const float*)d_in[11];
  const float* W_out  = (const float*)d_in[12];
  const float* b_out  = (const float*)d_in[13];
  const float* fc1_w  = (const float*)d_in[14];
  const float* fc1_b  = (const float*)d_in[15];
  const float* fc2_w  = (const float*)d_in[16];
  const float* fc2_b  = (const float*)d_in[17];

  char* base=(char*)d_ws; size_t off=0;
  auto alc=[&](size_t nb)->char*{ char* p=base+off; off=(off+nb+255)&~(size_t)255; return p; };
  float* wgt            = (float*)alc((size_t)MM*4*4);
  float* innorm         = (float*)alc((size_t)MM*4);
  int* par_g            = (int*)alc((size_t)MM*4);
  int* lvlorder         = (int*)alc((size_t)MM*4);
  int* lvlstart         = (int*)alc((size_t)BB*(NN+2)*4);
  int* nlvl             = (int*)alc((size_t)BB*4);
  unsigned short* xi_b  = (unsigned short*)alc((size_t)MM*DI*2);
  unsigned short* sz_b  = (unsigned short*)alc((size_t)MM*DI*2);   // contiguous after xi_b
  float* dbc            = (float*)alc((size_t)MM*18*4);
  unsigned short* dec_b = (unsigned short*)alc((size_t)MM*DI*2);
  unsigned short* bxh_b = (unsigned short*)alc((size_t)MM*DI*2);
  unsigned short* WinT  = (unsigned short*)alc((size_t)CC*1024*2);
  unsigned short* WoutT = (unsigned short*)alc((size_t)DI*CC*2);
  unsigned short* fc1T  = (unsigned short*)alc((size_t)CC*1024*2);
  unsigned short* fc2T  = (unsigned short*)alc((size_t)1024*CC*2);
  float* WxpT           = (float*)alc((size_t)DI*18*4);
  // lifetime-based aliases:
  unsigned short* xn    = (unsigned short*)dec_b;   // [MM][256] bf16; dead before k_dbx writes dec_b
  unsigned short* u_b   = sz_b;                     // in-place over sz
  float* x2             = (float*)dec_b;            // [MM][256] f32; dec dead after scan
  unsigned short* x2n   = bxh_b;                    // [MM][256] bf16; h dead after k_u
  unsigned short* g1_b  = xi_b;                     // [MM][1024] bf16; spans xi_b+sz_b

  k_wconv<<<dim3((256*1024+255)/256),dim3(256),0,stream>>>(W_in, WinT, 256,1024);
  k_wconv<<<dim3((512*256 +255)/256),dim3(256),0,stream>>>(W_out, WoutT, 512,256);
  k_wconv<<<dim3((256*1024+255)/256),dim3(256),0,stream>>>(fc1_w, fc1T, 256,1024);
  k_wconv<<<dim3((1024*256+255)/256),dim3(256),0,stream>>>(fc2_w, fc2T, 1024,256);
  k_t32  <<<dim3((512*18  +255)/256),dim3(256),0,stream>>>(W_xp, WxpT, 512,18);

  k_norm<<<dim3(MM/4),dim3(256),0,stream>>>(x, innorm);
  k_edge<<<dim3(MM/4),dim3(256),0,stream>>>(x, innorm, wgt);
  k_ln<<<dim3(MM/4),dim3(256),0,stream>>>(x, n1w, n1b, xn);

  // MST (blocks 0-15) + gemm<0> (2304 tile blocks) in one launch
  k_fused<<<dim3(BB + 288*8),dim3(256),0,stream>>>(xn, WinT, b_in, xi_b, sz_b,
                                                   wgt, par_g, lvlorder, lvlstart, nlvl);

  k_dbc<<<dim3(MM/4),dim3(256),0,stream>>>(xi_b, WxpT, dbc);
  k_dbx<<<dim3(MM),dim3(512),0,stream>>>(dbc, xi_b, W_dt, b_dt, A_log, dec_b, bxh_b);
  k_scan<<<dim3(BB*128),dim3(256),0,stream>>>(dec_b, bxh_b, par_g, lvlorder, lvlstart, nlvl);
  k_u<<<dim3(MM*64/256),dim3(256),0,stream>>>(bxh_b, xi_b, sz_b, dbc, Dp, u_b);
  k_gemm<1><<<dim3(288*2),dim3(256),0,stream>>>(u_b, WoutT, b_out, 256, 512, x, x2, nullptr, nullptr);

  k_ln<<<dim3(MM/4),dim3(256),0,stream>>>(x2, n2w, n2b, x2n);
  k_gemm<2><<<dim3(288*8),dim3(256),0,stream>>>(x2n, fc1T, fc1_b, 1024, 256, nullptr, nullptr, g1_b, nullptr);
  k_gemm<1><<<dim3(288*2),dim3(256),0,stream>>>(g1_b, fc2T, fc2_b, 256, 1024, x2, (float*)d_out, nullptr, nullptr);
}